// Round 9
// baseline (356.227 us; speedup 1.0000x reference)
//
#include <hip/hip_runtime.h>
#include <hip/hip_bf16.h>
#include <math.h>

typedef __attribute__((ext_vector_type(8))) short short8;      // 8 bf16 (4 VGPRs)
typedef __attribute__((ext_vector_type(4))) float f32x4;       // MFMA acc
typedef __attribute__((ext_vector_type(4))) unsigned short us4;

#define MFMA16(a,b,c) __builtin_amdgcn_mfma_f32_16x16x32_bf16((a),(b),(c),0,0,0)

// ---------------- workspace layout (bytes) ----------------
// W1cat: bf16 fragment-ordered [9][ks=8][nt=8][lane=64][j=8]
// W2cat: bf16 fragment-ordered [7][ks=4][nt=8][lane=64][j=8]
#define OFF_W1CAT   0u
#define OFF_W2CAT   589824u
#define OFF_B1      950272u    // f32 [9][128]
#define OFF_B2      954880u    // f32 [7][128]
#define OFF_LNG     958464u    // f32 [3][128] (D0,D1,S gains)
#define OFF_LNB     960000u    // f32 [3][128]
#define OFF_BSC     961536u    // f32 [2][128] B_g
#define OFF_BBI     962560u    // f32 [2][128] B_be
#define OFF_USAGE   963584u    // f32 [8]
#define OFF_W8      963712u    // f32 [32768][8]
#define OFF_W1T     2012288u   // f32 [257][128]  gate W1 transposed

__device__ __forceinline__ unsigned short f2bf(float f) {
  union { float f; unsigned u; } v; v.f = f;
  return (unsigned short)((v.u + 0x7fffu + ((v.u >> 16) & 1u)) >> 16);
}
// ---- fast activations (v_exp/v_rcp based; |err| << bf16 quantization) ----
__device__ __forceinline__ float frcp(float x) { return __builtin_amdgcn_rcpf(x); }
__device__ __forceinline__ float ftanh(float x) {
  float ax = fabsf(x);
  float t = __expf(-2.f * ax);
  float r = (1.f - t) * frcp(1.f + t);
  return copysignf(r, x);
}
__device__ __forceinline__ float fsilu(float x) {
  return x * frcp(1.f + __expf(-x));
}
__device__ __forceinline__ float fgelu(float x) {   // exact-erf form, A&S 7.1.26
  float ax = fabsf(x) * 0.70710678118654752f;
  float t = frcp(fmaf(0.3275911f, ax, 1.f));
  float p = fmaf(t, 1.061405429f, -1.453152027f);
  p = fmaf(t, p, 1.421413741f);
  p = fmaf(t, p, -0.284496736f);
  p = fmaf(t, p, 0.254829592f);
  p *= t;
  float erfv = copysignf(fmaf(-p, __expf(-ax * ax), 1.f), x);
  return 0.5f * x * (1.f + erfv);
}

// ============== prep: pack weights (fragment-ordered), fold conv ==============
__global__ __launch_bounds__(256) void prep_kernel(
    const float* __restrict__ A_W1, const float* __restrict__ A_b1,
    const float* __restrict__ A_W2, const float* __restrict__ A_b2,
    const float* __restrict__ B_W1, const float* __restrict__ B_b1,
    const float* __restrict__ B_g,  const float* __restrict__ B_be,
    const float* __restrict__ B_W2, const float* __restrict__ B_b2,
    const float* __restrict__ C_cw, const float* __restrict__ C_cb,
    const float* __restrict__ C_W,  const float* __restrict__ C_b,
    const float* __restrict__ D_W1, const float* __restrict__ D_b1,
    const float* __restrict__ D_g,  const float* __restrict__ D_be,
    const float* __restrict__ D_W2, const float* __restrict__ D_b2,
    const float* __restrict__ S_W1, const float* __restrict__ S_b1,
    const float* __restrict__ S_g,  const float* __restrict__ S_be,
    const float* __restrict__ S_W2, const float* __restrict__ S_b2,
    const float* __restrict__ G_W1,
    unsigned short* __restrict__ W1cat, unsigned short* __restrict__ W2cat,
    float* __restrict__ W1T,
    float* __restrict__ b1cat, float* __restrict__ b2cat,
    float* __restrict__ lng, float* __restrict__ lnb,
    float* __restrict__ bsc, float* __restrict__ bbi,
    float* __restrict__ usage)
{
  int tid = blockIdx.x * 256 + threadIdx.x;
  if (tid < 294912) {                       // W1cat, fragment order
    int g = tid >> 15, rem = tid & 32767;
    int j = rem & 7, lane = (rem >> 3) & 63, nt = (rem >> 9) & 7, ks = rem >> 12;
    int p = nt * 16 + (lane & 15);
    int k = ks * 32 + (lane >> 4) * 8 + j;
    int src = p * 256 + k;
    float v;
    if (g < 2)      v = A_W1[g * 32768 + src];
    else if (g < 4) v = B_W1[(g - 2) * 32768 + src];
    else if (g < 6) {                       // Weff = conv folded into C_W
      int e = g - 4;
      v = 0.f;
      for (int c = 0; c < 4; ++c)
        for (int jj = 0; jj < 3; ++jj) {
          int h = k + 1 - jj;
          if (h >= 0 && h < 256)
            v += C_cw[e*12 + c*3 + jj] * C_W[e*131072 + p*1024 + c*256 + h];
        }
    }
    else if (g < 8) v = D_W1[(g - 6) * 32768 + src];
    else            v = S_W1[src];
    W1cat[tid] = f2bf(v);
    return;
  }
  tid -= 294912;
  if (tid < 114688) {                       // W2cat, fragment order
    int g = tid >> 14, rem = tid & 16383;
    int j = rem & 7, lane = (rem >> 3) & 63, nt = (rem >> 9) & 7, ks = rem >> 12;
    int p = nt * 16 + (lane & 15);
    int k = ks * 32 + (lane >> 4) * 8 + j;
    int src = p * 128 + k;
    float v;
    if (g < 2)      v = A_W2[g * 16384 + src];
    else if (g < 4) v = B_W2[(g - 2) * 16384 + src];
    else if (g < 6) v = D_W2[(g - 4) * 16384 + src];
    else            v = S_W2[src];
    W2cat[tid] = f2bf(v);
    return;
  }
  tid -= 114688;
  if (tid < 32896) {                        // W1T[k][o] = G_W1[o][k]
    int k = tid / 128, o = tid % 128;
    W1T[tid] = G_W1[o * 257 + k];
    return;
  }
  tid -= 32896;
  if (tid < 1152) {                         // b1cat (C fold added by prep2)
    int g = tid / 128, p = tid % 128;
    float v;
    if (g < 2)      v = A_b1[tid];
    else if (g < 4) v = B_b1[p + (g - 2) * 128];
    else if (g < 6) v = C_b[(g - 4) * 128 + p];
    else if (g < 8) v = D_b1[p + (g - 6) * 128];
    else            v = S_b1[p];
    b1cat[tid] = v;
    return;
  }
  tid -= 1152;
  if (tid < 896) {                          // b2cat
    int g = tid / 128, p = tid % 128;
    float v;
    if (g < 2)      v = A_b2[tid];
    else if (g < 4) v = B_b2[p + (g - 2) * 128];
    else if (g < 6) v = D_b2[p + (g - 4) * 128];
    else            v = S_b2[p];
    b2cat[tid] = v;
    return;
  }
  tid -= 896;
  if (tid < 768) {                          // LN gains/biases (D0,D1,S)
    if (tid < 384) {
      int j = tid / 128, p = tid % 128;
      lng[tid] = (j < 2) ? D_g[tid] : S_g[p];
    } else {
      int q = tid - 384; int j = q / 128, p = q % 128;
      lnb[q] = (j < 2) ? D_be[q] : S_be[p];
    }
    return;
  }
  tid -= 768;
  if (tid < 512) {                          // B scale/shift
    if (tid < 256) bsc[tid] = B_g[tid];
    else           bbi[tid - 256] = B_be[tid - 256];
    return;
  }
  tid -= 512;
  if (tid < 8) usage[tid] = 0.f;
}

// prep2: parallel conv-bias fold
__global__ __launch_bounds__(256) void prep2_kernel(
    const float* __restrict__ C_cw_unused, const float* __restrict__ C_cb,
    const float* __restrict__ C_W, float* __restrict__ b1cat)
{
  int tid = blockIdx.x * 256 + threadIdx.x;   // 1024 threads: (e,p,c)
  int e = tid >> 9, rem = tid & 511;
  int p = rem >> 2, c = rem & 3;
  const float4* row = (const float4*)(C_W + e*131072 + p*1024 + c*256);
  float s = 0.f;
  for (int q = 0; q < 64; ++q) {
    float4 v = row[q];
    s += v.x + v.y + v.z + v.w;
  }
  atomicAdd(&b1cat[(4 + e) * 128 + p], C_cb[e * 4 + c] * s);
}

// ============== gate v3: token-on-lane, o-chains, exact np FMA order ==============
__global__ __launch_bounds__(512) void gate_np_kernel(
    const float* __restrict__ x, const int* __restrict__ modality,
    const float* __restrict__ W1T, const float* __restrict__ G_b1,
    const float* __restrict__ G_W2, const float* __restrict__ G_b2,
    float* __restrict__ w8full, float* __restrict__ usage)
{
  __shared__ unsigned char Ubuf[33024];     // xs [128][64] f32 (32KB) / ghs [64][129]
  __shared__ float ws2[8][132];
  __shared__ float lgs[64][9];
  float* xs  = (float*)Ubuf;
  float* ghs = (float*)Ubuf;
  const int tid = threadIdx.x;
  const int wv = __builtin_amdgcn_readfirstlane(tid >> 6);
  const int lane = tid & 63;
  const int tb = blockIdx.x * 64;
  const int o0 = wv * 16;
  const int t = lane;

  for (int i = tid; i < 1024; i += 512) ws2[i >> 7][i & 127] = G_W2[i];

  float acc[16];
#pragma unroll
  for (int j = 0; j < 16; ++j) acc[j] = 0.f;

  for (int p = 0; p < 2; ++p) {
    __syncthreads();                        // previous phase fully consumed
#pragma unroll
    for (int it = 0; it < 4; ++it) {
      int f = it * 512 + tid;               // float4 index in [64 rows][32 f4]
      int tt = f >> 5, c4 = f & 31;
      int kk = c4 * 4;
      const float4 v = *(const float4*)(x + (size_t)(tb + tt) * 256 + p * 128 + kk);
      int col = tt ^ (((kk >> 4) & 7) << 3);
      xs[(kk + 0) * 64 + col] = v.x;
      xs[(kk + 1) * 64 + col] = v.y;
      xs[(kk + 2) * 64 + col] = v.z;
      xs[(kk + 3) * 64 + col] = v.w;
    }
    __syncthreads();
    const float* wbase = W1T + (size_t)(p * 128) * 128 + o0;
    for (int kk = 0; kk < 128; ++kk) {
      float xv = xs[kk * 64 + (t ^ (((kk >> 4) & 7) << 3))];
      const float* wk = wbase + (size_t)kk * 128;
#pragma unroll
      for (int j = 0; j < 16; ++j)
        acc[j] = fmaf(xv, wk[j], acc[j]);   // exact sequential-k chain
    }
  }
  {
    float xv = (float)modality[tb + t];     // k = 256 (mod column)
    const float* wk = W1T + (size_t)256 * 128 + o0;
#pragma unroll
    for (int j = 0; j < 16; ++j)
      acc[j] = fmaf(xv, wk[j], acc[j]);
  }
  __syncthreads();                          // xs dead -> reuse as ghs
#pragma unroll
  for (int j = 0; j < 16; ++j)
    ghs[t * 129 + o0 + j] = (float)tanh((double)(acc[j] + G_b1[o0 + j]));
  __syncthreads();

  {
    int t2 = tid >> 3, e2 = tid & 7;
    float lg = 0.f;
    for (int o2 = 0; o2 < 128; ++o2)
      lg = fmaf(ghs[t2 * 129 + o2], ws2[e2][o2], lg);
    float s = (lg + G_b2[e2]) / 0.7f;       // f32 div
    lgs[t2][e2] = fminf(fmaxf(s, -10.f), 10.f);
  }
  __syncthreads();

  if (wv == 0) {                            // 64 tokens on 64 lanes
    int token = tb + lane;
    float v[8];
#pragma unroll
    for (int e = 0; e < 8; ++e) v[e] = lgs[lane][e];
    float tv[4]; int ti[4]; unsigned msk = 0;
    for (int kk = 0; kk < 4; ++kk) {        // ties -> lowest idx
      float best = -1e30f; int bi = 0;
      for (int e = 0; e < 8; ++e)
        if (!((msk >> e) & 1u) && v[e] > best) { best = v[e]; bi = e; }
      tv[kk] = best; ti[kk] = bi; msk |= 1u << bi;
    }
    float mx = tv[0], den = 0.f, wk4[4];
#pragma unroll
    for (int kk = 0; kk < 4; ++kk) { wk4[kk] = expf(tv[kk] - mx); den += wk4[kk]; }
#pragma unroll
    for (int e = 0; e < 8; ++e) {
      float val = 0.f;
#pragma unroll
      for (int kk = 0; kk < 4; ++kk) if (ti[kk] == e) val = wk4[kk] / den;
      w8full[(size_t)token * 8 + e] = val;
    }
    float uw[8];
    float dall = 0.f, pe[8];
#pragma unroll
    for (int e = 0; e < 8; ++e) { pe[e] = expf(v[e] - mx); dall += pe[e]; }
#pragma unroll
    for (int e = 0; e < 8; ++e) uw[e] = pe[e] / dall;
    for (int m = 1; m <= 32; m <<= 1)
#pragma unroll
      for (int e = 0; e < 8; ++e) uw[e] += __shfl_xor(uw[e], m);
    if (lane == 0)
      for (int e = 0; e < 8; ++e) atomicAdd(usage + e, uw[e]);
  }
}

// ---- per-tile epilogue + GEMM2 + combine (groups 0,1,2,3,6,7) ----
__device__ __forceinline__ void expert_tail(
    f32x4 (&acc)[8], int g, int type, int tt, int tb,
    const float* __restrict__ b1, const float* __restrict__ b2cat,
    const float* __restrict__ bsc, const float* __restrict__ bbi,
    const float* __restrict__ lng, const float* __restrict__ lnb,
    const float* __restrict__ w8full, const short8* __restrict__ W2f,
    unsigned char* HS, float* pacc_f, int l15, int l4, int lane, float RS)
{
  f32x4 zero = {0.f, 0.f, 0.f, 0.f};
#pragma unroll
  for (int r = 0; r < 4; ++r)
#pragma unroll
    for (int nt = 0; nt < 8; ++nt) {
      float h = acc[nt][r] + b1[nt * 16 + l15];
      if (type == 0)      h = fmaxf(h, 0.f);
      else if (type == 1) {
        int col = (g - 2) * 128 + nt * 16 + l15;
        h = ftanh(h) * RS * bsc[col] + bbi[col];
      }
      else                h = fsilu(h);             // silu (D)
      acc[nt][r] = h;
    }
  if (type == 3) {                      // D layernorm (in-wave shuffles)
    int li = g - 6;
#pragma unroll
    for (int r = 0; r < 4; ++r) {
      float s1 = 0.f, s2 = 0.f;
#pragma unroll
      for (int nt = 0; nt < 8; ++nt) { float h = acc[nt][r]; s1 += h; s2 += h * h; }
      for (int m = 1; m <= 8; m <<= 1) { s1 += __shfl_xor(s1, m); s2 += __shfl_xor(s2, m); }
      float mu = s1 * (1.f / 128.f);
      float var = s2 * (1.f / 128.f) - mu * mu;
      float sc = __builtin_amdgcn_rsqf(var + 1e-5f);
#pragma unroll
      for (int nt = 0; nt < 8; ++nt) {
        int col = nt * 16 + l15;
        acc[nt][r] = (acc[nt][r] - mu) * sc * lng[li * 128 + col] + lnb[li * 128 + col];
      }
    }
  }
  // write h tile (bf16, swizzled, per-wave region)
#pragma unroll
  for (int r = 0; r < 4; ++r) {
    int row = l4 * 4 + r;
#pragma unroll
    for (int nt = 0; nt < 8; ++nt) {
      int bytecol = (nt * 16 + l15) * 2;
      int addr = row * 256 + ((((bytecol >> 4) ^ (row & 7)) << 4) | (bytecol & 15));
      *(unsigned short*)(HS + addr) = f2bf(acc[nt][r]);
    }
  }
  // h transpose -> registers
  short8 a2[4];
#pragma unroll
  for (int ks = 0; ks < 4; ++ks) {
    int ar = l15 * 256 + ((((ks * 4 + l4) ^ (l15 & 7)) << 4));
    a2[ks] = *(const short8*)(HS + ar);
  }
  // GEMM2
  const int g2 = (g < 4) ? g : (g - 2);
  const short8* bg2 = W2f + (size_t)(g2 * 32) * 64 + lane;
  f32x4 acc2[8];
#pragma unroll
  for (int nt = 0; nt < 8; ++nt) acc2[nt] = zero;
#pragma unroll
  for (int ks = 0; ks < 4; ++ks)
#pragma unroll
    for (int nt = 0; nt < 8; ++nt)
      acc2[nt] = MFMA16(a2[ks], bg2[ks * 512 + nt * 64], acc2[nt]);
  const float* b2 = b2cat + g2 * 128;
#pragma unroll
  for (int r = 0; r < 4; ++r) {
    float wv_ = w8full[(size_t)(tb + tt * 16 + l4 * 4 + r) * 8 + g];
#pragma unroll
    for (int nt = 0; nt < 8; ++nt)
      atomicAdd(&pacc_f[tt * 2048 + (l4 * 4 + r) * 128 + nt * 16 + l15],
                wv_ * (acc2[nt][r] + b2[nt * 16 + l15]));
  }
}

// ============== moe v7: 2 token-tiles/block, B-frag reuse in GEMM1 ==============
__global__ __launch_bounds__(512, 4) void moe_kernel(
    const float* __restrict__ x,
    const unsigned short* __restrict__ W1cat, const unsigned short* __restrict__ W2cat,
    const float* __restrict__ b1cat, const float* __restrict__ b2cat,
    const float* __restrict__ lng, const float* __restrict__ lnb,
    const float* __restrict__ bsc, const float* __restrict__ bbi,
    const float* __restrict__ w8full, float* __restrict__ out)
{
  // LDS: XS0 8K | XS1 8K | HSb 8*4K | pacc 16K | partS 2K  = 66.5 KB
  __shared__ unsigned char smem[67584];
  unsigned char* XS0 = smem;
  unsigned char* XS1 = smem + 8192;
  unsigned char* HSb = smem + 16384;
  float* pacc_f = (float*)(smem + 49152);   // [2][16][128]
  float* partS  = (float*)(smem + 65536);   // [2 tiles][2 kinds][128]

  const int wv = threadIdx.x >> 6, lane = threadIdx.x & 63;
  const int l15 = lane & 15, l4 = lane >> 4;
  const int tb = blockIdx.x * 32;
  const int g = wv;
  const short8* W1f = (const short8*)W1cat;
  const short8* W2f = (const short8*)W2cat;
  unsigned char* HS = HSb + wv * 4096;
  unsigned char* HS_S0 = HSb + 4 * 4096;    // waves 4,5 (C) never use their HS
  unsigned char* HS_S1 = HSb + 5 * 4096;

  for (int i = threadIdx.x; i < 4096; i += 512) pacc_f[i] = 0.f;
  // stage both x tiles (32 rows), wave wv stages rows wv*4..wv*4+3
#pragma unroll
  for (int i = 0; i < 4; ++i) {
    int r = wv * 4 + i;
    int lr = r & 15;
    unsigned char* XS = (r < 16) ? XS0 : XS1;
    const float4 v = *(const float4*)(x + (size_t)(tb + r) * 256 + lane * 4);
    float vv[4] = {v.x, v.y, v.z, v.w};
    us4 hi;
#pragma unroll
    for (int j = 0; j < 4; ++j) hi[j] = f2bf(vv[j]);
    int addr = lr * 512 + ((((lane >> 1) ^ (lr & 7)) << 4) | ((lane & 1) << 3));
    *(us4*)(XS + addr) = hi;
  }
  __syncthreads();

  f32x4 zero = {0.f, 0.f, 0.f, 0.f};
  const float RS = 1.0f / sqrtf(1.0f + 1e-5f);

  // ---- GEMM1 for this wave's group, both tiles share B fragments ----
  {
    const short8* bg = W1f + (size_t)(g * 64) * 64 + lane;
    f32x4 acc0[8], acc1[8];
#pragma unroll
    for (int nt = 0; nt < 8; ++nt) { acc0[nt] = zero; acc1[nt] = zero; }
#pragma unroll
    for (int ks = 0; ks < 8; ++ks) {
      int ar = l15 * 512 + ((((ks * 4 + l4) ^ (l15 & 7)) << 4));
      short8 a0 = *(const short8*)(XS0 + ar);
      short8 a1 = *(const short8*)(XS1 + ar);
#pragma unroll
      for (int nt = 0; nt < 8; ++nt) {
        short8 b = bg[ks * 512 + nt * 64];
        acc0[nt] = MFMA16(a0, b, acc0[nt]);
        acc1[nt] = MFMA16(a1, b, acc1[nt]);
      }
    }
    const float* b1 = b1cat + g * 128;
    const int type = (g < 2) ? 0 : (g < 4) ? 1 : (g < 6) ? 2 : 3;

    if (type == 2) {                        // C: fast gelu -> weighted pacc (both tiles)
#pragma unroll
      for (int tt = 0; tt < 2; ++tt)
#pragma unroll
        for (int r = 0; r < 4; ++r) {
          float wv_ = w8full[(size_t)(tb + tt * 16 + l4 * 4 + r) * 8 + g];
#pragma unroll
          for (int nt = 0; nt < 8; ++nt) {
            float h = fgelu((tt ? acc1[nt][r] : acc0[nt][r]) + b1[nt * 16 + l15]);
            atomicAdd(&pacc_f[tt * 2048 + (l4 * 4 + r) * 128 + nt * 16 + l15], wv_ * h);
          }
        }
    } else {
      expert_tail(acc0, g, type, 0, tb, b1, b2cat, bsc, bbi, lng, lnb,
                  w8full, W2f, HS, pacc_f, l15, l4, lane, RS);
      expert_tail(acc1, g, type, 1, tb, b1, b2cat, bsc, bbi, lng, lnb,
                  w8full, W2f, HS, pacc_f, l15, l4, lane, RS);
    }
  }

  // ---- S network: wave wv owns 16-col block; B/C frags shared across tiles ----
  {
    short8 bS[8];
#pragma unroll
    for (int ks = 0; ks < 8; ++ks)
      bS[ks] = W1f[((size_t)(64 + ks) * 8 + wv) * 64 + lane];
    f32x4 accS0 = zero, accS1 = zero;
#pragma unroll
    for (int ks = 0; ks < 8; ++ks) {
      int ar = l15 * 512 + ((((ks * 4 + l4) ^ (l15 & 7)) << 4));
      accS0 = MFMA16(*(const short8*)(XS0 + ar), bS[ks], accS0);
      accS1 = MFMA16(*(const short8*)(XS1 + ar), bS[ks], accS1);
    }
    float bS1v = b1cat[8 * 128 + wv * 16 + l15];
#pragma unroll
    for (int r = 0; r < 4; ++r) {
      accS0[r] = fmaxf(accS0[r] + bS1v, 0.f);
      accS1[r] = fmaxf(accS1[r] + bS1v, 0.f);
    }
#pragma unroll
    for (int tt = 0; tt < 2; ++tt)
#pragma unroll
      for (int r = 0; r < 4; ++r) {
        float h = tt ? accS1[r] : accS0[r];
        float s1 = h, s2 = h * h;
        for (int m = 1; m <= 8; m <<= 1) { s1 += __shfl_xor(s1, m); s2 += __shfl_xor(s2, m); }
        if (l15 == 0) {
          partS[tt * 256 + wv * 16 + l4 * 4 + r] = s1;
          partS[tt * 256 + 128 + wv * 16 + l4 * 4 + r] = s2;
        }
      }
    __syncthreads();
#pragma unroll
    for (int tt = 0; tt < 2; ++tt) {
      unsigned char* HS_S = tt ? HS_S1 : HS_S0;
#pragma unroll
      for (int r = 0; r < 4; ++r) {
        int row = l4 * 4 + r;
        float s1 = 0.f, s2 = 0.f;
#pragma unroll
        for (int q = 0; q < 8; ++q) {
          s1 += partS[tt * 256 + q * 16 + row];
          s2 += partS[tt * 256 + 128 + q * 16 + row];
        }
        float mu = s1 * (1.f / 128.f);
        float var = s2 * (1.f / 128.f) - mu * mu;
        float sc = __builtin_amdgcn_rsqf(var + 1e-5f);
        int col = wv * 16 + l15;
        float h = tt ? accS1[r] : accS0[r];
        float hn = (h - mu) * sc * lng[2 * 128 + col] + lnb[2 * 128 + col];
        int bytecol = col * 2;
        int addr = row * 256 + ((((bytecol >> 4) ^ (row & 7)) << 4) | (bytecol & 15));
        *(unsigned short*)(HS_S + addr) = f2bf(hn);
      }
    }
    __syncthreads();
    short8 cS[4];
#pragma unroll
    for (int ks = 0; ks < 4; ++ks)
      cS[ks] = W2f[((size_t)(24 + ks) * 8 + wv) * 64 + lane];
    f32x4 a2S0 = zero, a2S1 = zero;
#pragma unroll
    for (int ks = 0; ks < 4; ++ks) {
      int ar = l15 * 256 + ((((ks * 4 + l4) ^ (l15 & 7)) << 4));
      a2S0 = MFMA16(*(const short8*)(HS_S0 + ar), cS[ks], a2S0);
      a2S1 = MFMA16(*(const short8*)(HS_S1 + ar), cS[ks], a2S1);
    }
    float b2S = b2cat[6 * 128 + wv * 16 + l15];
#pragma unroll
    for (int tt = 0; tt < 2; ++tt)
#pragma unroll
      for (int r = 0; r < 4; ++r)
        out[(size_t)(tb + tt * 16 + l4 * 4 + r) * 128 + wv * 16 + l15] =
            (tt ? a2S1[r] : a2S0[r]) + b2S;
  }

  __syncthreads();
  for (int i = threadIdx.x; i < 4096; i += 512)
    out[4194304 + (size_t)tb * 128 + i] = pacc_f[i];
}

// ============== aux scalar ==============
__global__ void aux_kernel(const float* __restrict__ usage, float* __restrict__ out) {
  if (threadIdx.x == 0 && blockIdx.x == 0) {
    float a = 0.f;
    for (int e = 0; e < 8; ++e) {
      float u = usage[e] * (1.0f / 32768.0f);
      a += 0.125f * (logf(0.125f) - logf(u + 1e-10f));
    }
    out[8388608] = a * 0.125f;
  }
}

extern "C" void kernel_launch(void* const* d_in, const int* in_sizes, int n_in,
                              void* d_out, int out_size, void* d_ws, size_t ws_size,
                              hipStream_t stream) {
  (void)in_sizes; (void)n_in; (void)out_size; (void)ws_size;
  const float* x    = (const float*)d_in[0];
  const int*   mod  = (const int*)d_in[1];
  const float* A_W1 = (const float*)d_in[2];
  const float* A_b1 = (const float*)d_in[3];
  const float* A_W2 = (const float*)d_in[4];
  const float* A_b2 = (const float*)d_in[5];
  const float* B_W1 = (const float*)d_in[6];
  const float* B_b1 = (const float*)d_in[7];
  const float* B_g  = (const float*)d_in[8];
  const float* B_be = (const float*)d_in[9];
  const float* B_W2 = (const float*)d_in[10];
  const float* B_b2 = (const float*)d_in[11];
  const float* C_cw = (const float*)d_in[12];
  const float* C_cb = (const float*)d_in[13];
  const float* C_W  = (const float*)d_in[14];
  const float* C_b  = (const float*)d_in[15];
  const float* D_W1 = (const float*)d_in[16];
  const float* D_b1 = (const float*)d_in[17];
  const float* D_g  = (const float*)d_in[18];
  const float* D_be = (const float*)d_in[19];
  const float* D_W2 = (const float*)d_in[20];
  const float* D_b2 = (const float*)d_in[21];
  const float* S_W1 = (const float*)d_in[22];
  const float* S_b1 = (const float*)d_in[23];
  const float* S_g  = (const float*)d_in[24];
  const float* S_be = (const float*)d_in[25];
  const float* S_W2 = (const float*)d_in[26];
  const float* S_b2 = (const float*)d_in[27];
  const float* G_W1 = (const float*)d_in[28];
  const float* G_b1 = (const float*)d_in[29];
  const float* G_W2 = (const float*)d_in[30];
  const float* G_b2 = (const float*)d_in[31];

  char* ws = (char*)d_ws;
  unsigned short* W1cat = (unsigned short*)(ws + OFF_W1CAT);
  unsigned short* W2cat = (unsigned short*)(ws + OFF_W2CAT);
  float* W1T    = (float*)(ws + OFF_W1T);
  float* b1cat  = (float*)(ws + OFF_B1);
  float* b2cat  = (float*)(ws + OFF_B2);
  float* lng    = (float*)(ws + OFF_LNG);
  float* lnb    = (float*)(ws + OFF_LNB);
  float* bsc    = (float*)(ws + OFF_BSC);
  float* bbi    = (float*)(ws + OFF_BBI);
  float* usage  = (float*)(ws + OFF_USAGE);
  float* w8full = (float*)(ws + OFF_W8);
  float* out    = (float*)d_out;

  prep_kernel<<<1742, 256, 0, stream>>>(A_W1, A_b1, A_W2, A_b2, B_W1, B_b1, B_g, B_be,
      B_W2, B_b2, C_cw, C_cb, C_W, C_b, D_W1, D_b1, D_g, D_be, D_W2, D_b2,
      S_W1, S_b1, S_g, S_be, S_W2, S_b2, G_W1,
      W1cat, W2cat, W1T, b1cat, b2cat, lng, lnb, bsc, bbi, usage);
  prep2_kernel<<<4, 256, 0, stream>>>(C_cw, C_cb, C_W, b1cat);
  gate_np_kernel<<<512, 512, 0, stream>>>(x, mod, W1T, G_b1, G_W2, G_b2,
      w8full, usage);
  moe_kernel<<<1024, 512, 0, stream>>>(x, W1cat, W2cat, b1cat, b2cat, lng, lnb,
      bsc, bbi, w8full, out);
  aux_kernel<<<1, 64, 0, stream>>>(usage, out);
}

// Round 10
// 312.901 us; speedup vs baseline: 1.1385x; 1.1385x over previous
//
#include <hip/hip_runtime.h>
#include <hip/hip_bf16.h>
#include <math.h>

typedef __attribute__((ext_vector_type(8))) short short8;      // 8 bf16 (4 VGPRs)
typedef __attribute__((ext_vector_type(4))) float f32x4;       // MFMA acc
typedef __attribute__((ext_vector_type(4))) unsigned short us4;

#define MFMA16(a,b,c) __builtin_amdgcn_mfma_f32_16x16x32_bf16((a),(b),(c),0,0,0)

// ---------------- workspace layout (bytes) ----------------
// W1cat: bf16 fragment-ordered [9][ks=8][nt=8][lane=64][j=8]
// W2cat: bf16 fragment-ordered [7][ks=4][nt=8][lane=64][j=8]
#define OFF_W1CAT   0u
#define OFF_W2CAT   589824u
#define OFF_B1      950272u    // f32 [9][128]
#define OFF_B2      954880u    // f32 [7][128]
#define OFF_LNG     958464u    // f32 [3][128] (D0,D1,S gains)
#define OFF_LNB     960000u    // f32 [3][128]
#define OFF_BSC     961536u    // f32 [2][128] B_g
#define OFF_BBI     962560u    // f32 [2][128] B_be
#define OFF_USAGE   963584u    // f32 [8]
#define OFF_W8      963712u    // f32 [32768][8]
#define OFF_W1T     2012288u   // f32 [257][128]  gate W1 transposed

__device__ __forceinline__ unsigned short f2bf(float f) {
  union { float f; unsigned u; } v; v.f = f;
  return (unsigned short)((v.u + 0x7fffu + ((v.u >> 16) & 1u)) >> 16);
}
// ---- fast activations (v_exp/v_rcp based; |err| << bf16 quantization) ----
__device__ __forceinline__ float frcp(float x) { return __builtin_amdgcn_rcpf(x); }
__device__ __forceinline__ float ftanh(float x) {
  float ax = fabsf(x);
  float t = __expf(-2.f * ax);
  float r = (1.f - t) * frcp(1.f + t);
  return copysignf(r, x);
}
__device__ __forceinline__ float fsilu(float x) {
  return x * frcp(1.f + __expf(-x));
}
__device__ __forceinline__ float fgelu(float x) {   // exact-erf form, A&S 7.1.26
  float ax = fabsf(x) * 0.70710678118654752f;
  float t = frcp(fmaf(0.3275911f, ax, 1.f));
  float p = fmaf(t, 1.061405429f, -1.453152027f);
  p = fmaf(t, p, 1.421413741f);
  p = fmaf(t, p, -0.284496736f);
  p = fmaf(t, p, 0.254829592f);
  p *= t;
  float erfv = copysignf(fmaf(-p, __expf(-ax * ax), 1.f), x);
  return 0.5f * x * (1.f + erfv);
}

// ============== prep: pack weights (fragment-ordered), fold conv ==============
__global__ __launch_bounds__(256) void prep_kernel(
    const float* __restrict__ A_W1, const float* __restrict__ A_b1,
    const float* __restrict__ A_W2, const float* __restrict__ A_b2,
    const float* __restrict__ B_W1, const float* __restrict__ B_b1,
    const float* __restrict__ B_g,  const float* __restrict__ B_be,
    const float* __restrict__ B_W2, const float* __restrict__ B_b2,
    const float* __restrict__ C_cw, const float* __restrict__ C_cb,
    const float* __restrict__ C_W,  const float* __restrict__ C_b,
    const float* __restrict__ D_W1, const float* __restrict__ D_b1,
    const float* __restrict__ D_g,  const float* __restrict__ D_be,
    const float* __restrict__ D_W2, const float* __restrict__ D_b2,
    const float* __restrict__ S_W1, const float* __restrict__ S_b1,
    const float* __restrict__ S_g,  const float* __restrict__ S_be,
    const float* __restrict__ S_W2, const float* __restrict__ S_b2,
    const float* __restrict__ G_W1,
    unsigned short* __restrict__ W1cat, unsigned short* __restrict__ W2cat,
    float* __restrict__ W1T,
    float* __restrict__ b1cat, float* __restrict__ b2cat,
    float* __restrict__ lng, float* __restrict__ lnb,
    float* __restrict__ bsc, float* __restrict__ bbi,
    float* __restrict__ usage)
{
  int tid = blockIdx.x * 256 + threadIdx.x;
  if (tid < 294912) {                       // W1cat, fragment order
    int g = tid >> 15, rem = tid & 32767;
    int j = rem & 7, lane = (rem >> 3) & 63, nt = (rem >> 9) & 7, ks = rem >> 12;
    int p = nt * 16 + (lane & 15);
    int k = ks * 32 + (lane >> 4) * 8 + j;
    int src = p * 256 + k;
    float v;
    if (g < 2)      v = A_W1[g * 32768 + src];
    else if (g < 4) v = B_W1[(g - 2) * 32768 + src];
    else if (g < 6) {                       // Weff = conv folded into C_W
      int e = g - 4;
      v = 0.f;
      for (int c = 0; c < 4; ++c)
        for (int jj = 0; jj < 3; ++jj) {
          int h = k + 1 - jj;
          if (h >= 0 && h < 256)
            v += C_cw[e*12 + c*3 + jj] * C_W[e*131072 + p*1024 + c*256 + h];
        }
    }
    else if (g < 8) v = D_W1[(g - 6) * 32768 + src];
    else            v = S_W1[src];
    W1cat[tid] = f2bf(v);
    return;
  }
  tid -= 294912;
  if (tid < 114688) {                       // W2cat, fragment order
    int g = tid >> 14, rem = tid & 16383;
    int j = rem & 7, lane = (rem >> 3) & 63, nt = (rem >> 9) & 7, ks = rem >> 12;
    int p = nt * 16 + (lane & 15);
    int k = ks * 32 + (lane >> 4) * 8 + j;
    int src = p * 128 + k;
    float v;
    if (g < 2)      v = A_W2[g * 16384 + src];
    else if (g < 4) v = B_W2[(g - 2) * 16384 + src];
    else if (g < 6) v = D_W2[(g - 4) * 16384 + src];
    else            v = S_W2[src];
    W2cat[tid] = f2bf(v);
    return;
  }
  tid -= 114688;
  if (tid < 32896) {                        // W1T[k][o] = G_W1[o][k]
    int k = tid / 128, o = tid % 128;
    W1T[tid] = G_W1[o * 257 + k];
    return;
  }
  tid -= 32896;
  if (tid < 1152) {                         // b1cat (C fold added by prep2)
    int g = tid / 128, p = tid % 128;
    float v;
    if (g < 2)      v = A_b1[tid];
    else if (g < 4) v = B_b1[p + (g - 2) * 128];
    else if (g < 6) v = C_b[(g - 4) * 128 + p];
    else if (g < 8) v = D_b1[p + (g - 6) * 128];
    else            v = S_b1[p];
    b1cat[tid] = v;
    return;
  }
  tid -= 1152;
  if (tid < 896) {                          // b2cat
    int g = tid / 128, p = tid % 128;
    float v;
    if (g < 2)      v = A_b2[tid];
    else if (g < 4) v = B_b2[p + (g - 2) * 128];
    else if (g < 6) v = D_b2[p + (g - 4) * 128];
    else            v = S_b2[p];
    b2cat[tid] = v;
    return;
  }
  tid -= 896;
  if (tid < 768) {                          // LN gains/biases (D0,D1,S)
    if (tid < 384) {
      int j = tid / 128, p = tid % 128;
      lng[tid] = (j < 2) ? D_g[tid] : S_g[p];
    } else {
      int q = tid - 384; int j = q / 128, p = q % 128;
      lnb[q] = (j < 2) ? D_be[q] : S_be[p];
    }
    return;
  }
  tid -= 768;
  if (tid < 512) {                          // B scale/shift
    if (tid < 256) bsc[tid] = B_g[tid];
    else           bbi[tid - 256] = B_be[tid - 256];
    return;
  }
  tid -= 512;
  if (tid < 8) usage[tid] = 0.f;
}

// prep2: parallel conv-bias fold
__global__ __launch_bounds__(256) void prep2_kernel(
    const float* __restrict__ C_cw_unused, const float* __restrict__ C_cb,
    const float* __restrict__ C_W, float* __restrict__ b1cat)
{
  int tid = blockIdx.x * 256 + threadIdx.x;   // 1024 threads: (e,p,c)
  int e = tid >> 9, rem = tid & 511;
  int p = rem >> 2, c = rem & 3;
  const float4* row = (const float4*)(C_W + e*131072 + p*1024 + c*256);
  float s = 0.f;
  for (int q = 0; q < 64; ++q) {
    float4 v = row[q];
    s += v.x + v.y + v.z + v.w;
  }
  atomicAdd(&b1cat[(4 + e) * 128 + p], C_cb[e * 4 + c] * s);
}

// zero the private-output region (re-run every launch, before moe atomics)
__global__ __launch_bounds__(256) void zero_kernel(float* __restrict__ out) {
  int i = blockIdx.x * 256 + threadIdx.x;
  float4 z = {0.f, 0.f, 0.f, 0.f};
  float4* p = (float4*)(out + 4194304);
  p[i * 2] = z;
  p[i * 2 + 1] = z;
}

// ============== gate v3: token-on-lane, o-chains, exact np FMA order ==============
__global__ __launch_bounds__(512) void gate_np_kernel(
    const float* __restrict__ x, const int* __restrict__ modality,
    const float* __restrict__ W1T, const float* __restrict__ G_b1,
    const float* __restrict__ G_W2, const float* __restrict__ G_b2,
    float* __restrict__ w8full, float* __restrict__ usage)
{
  __shared__ unsigned char Ubuf[33024];     // xs [128][64] f32 (32KB) / ghs [64][129]
  __shared__ float ws2[8][132];
  __shared__ float lgs[64][9];
  float* xs  = (float*)Ubuf;
  float* ghs = (float*)Ubuf;
  const int tid = threadIdx.x;
  const int wv = __builtin_amdgcn_readfirstlane(tid >> 6);
  const int lane = tid & 63;
  const int tb = blockIdx.x * 64;
  const int o0 = wv * 16;
  const int t = lane;

  for (int i = tid; i < 1024; i += 512) ws2[i >> 7][i & 127] = G_W2[i];

  float acc[16];
#pragma unroll
  for (int j = 0; j < 16; ++j) acc[j] = 0.f;

  for (int p = 0; p < 2; ++p) {
    __syncthreads();                        // previous phase fully consumed
#pragma unroll
    for (int it = 0; it < 4; ++it) {
      int f = it * 512 + tid;               // float4 index in [64 rows][32 f4]
      int tt = f >> 5, c4 = f & 31;
      int kk = c4 * 4;
      const float4 v = *(const float4*)(x + (size_t)(tb + tt) * 256 + p * 128 + kk);
      int col = tt ^ (((kk >> 4) & 7) << 3);
      xs[(kk + 0) * 64 + col] = v.x;
      xs[(kk + 1) * 64 + col] = v.y;
      xs[(kk + 2) * 64 + col] = v.z;
      xs[(kk + 3) * 64 + col] = v.w;
    }
    __syncthreads();
    const float* wbase = W1T + (size_t)(p * 128) * 128 + o0;
    for (int kk = 0; kk < 128; ++kk) {
      float xv = xs[kk * 64 + (t ^ (((kk >> 4) & 7) << 3))];
      const float* wk = wbase + (size_t)kk * 128;
#pragma unroll
      for (int j = 0; j < 16; ++j)
        acc[j] = fmaf(xv, wk[j], acc[j]);   // exact sequential-k chain
    }
  }
  {
    float xv = (float)modality[tb + t];     // k = 256 (mod column)
    const float* wk = W1T + (size_t)256 * 128 + o0;
#pragma unroll
    for (int j = 0; j < 16; ++j)
      acc[j] = fmaf(xv, wk[j], acc[j]);
  }
  __syncthreads();                          // xs dead -> reuse as ghs
#pragma unroll
  for (int j = 0; j < 16; ++j)
    ghs[t * 129 + o0 + j] = (float)tanh((double)(acc[j] + G_b1[o0 + j]));
  __syncthreads();

  {
    int t2 = tid >> 3, e2 = tid & 7;
    float lg = 0.f;
    for (int o2 = 0; o2 < 128; ++o2)
      lg = fmaf(ghs[t2 * 129 + o2], ws2[e2][o2], lg);
    float s = (lg + G_b2[e2]) / 0.7f;       // f32 div
    lgs[t2][e2] = fminf(fmaxf(s, -10.f), 10.f);
  }
  __syncthreads();

  if (wv == 0) {                            // 64 tokens on 64 lanes
    int token = tb + lane;
    float v[8];
#pragma unroll
    for (int e = 0; e < 8; ++e) v[e] = lgs[lane][e];
    float tv[4]; int ti[4]; unsigned msk = 0;
    for (int kk = 0; kk < 4; ++kk) {        // ties -> lowest idx
      float best = -1e30f; int bi = 0;
      for (int e = 0; e < 8; ++e)
        if (!((msk >> e) & 1u) && v[e] > best) { best = v[e]; bi = e; }
      tv[kk] = best; ti[kk] = bi; msk |= 1u << bi;
    }
    float mx = tv[0], den = 0.f, wk4[4];
#pragma unroll
    for (int kk = 0; kk < 4; ++kk) { wk4[kk] = expf(tv[kk] - mx); den += wk4[kk]; }
#pragma unroll
    for (int e = 0; e < 8; ++e) {
      float val = 0.f;
#pragma unroll
      for (int kk = 0; kk < 4; ++kk) if (ti[kk] == e) val = wk4[kk] / den;
      w8full[(size_t)token * 8 + e] = val;
    }
    float uw[8];
    float dall = 0.f, pe[8];
#pragma unroll
    for (int e = 0; e < 8; ++e) { pe[e] = expf(v[e] - mx); dall += pe[e]; }
#pragma unroll
    for (int e = 0; e < 8; ++e) uw[e] = pe[e] / dall;
    for (int m = 1; m <= 32; m <<= 1)
#pragma unroll
      for (int e = 0; e < 8; ++e) uw[e] += __shfl_xor(uw[e], m);
    if (lane == 0)
      for (int e = 0; e < 8; ++e) atomicAdd(usage + e, uw[e]);
  }
}

// ============== moe v8: fam-per-block, LDS-resident weights, atomic combine ==============
// grid = 9 fams x 256 token-blocks. Block: stage fam W1(64K)+W2(32K) to LDS once
// for 128 tokens; 8 free-running waves (16 tokens each, A-frags in registers).
// Private fams: global f32 atomicAdd into pre-zeroed out; shared fam stores.
__global__ __launch_bounds__(512, 2) void moe_kernel(
    const float* __restrict__ x,
    const unsigned short* __restrict__ W1cat, const unsigned short* __restrict__ W2cat,
    const float* __restrict__ b1cat, const float* __restrict__ b2cat,
    const float* __restrict__ lng, const float* __restrict__ lnb,
    const float* __restrict__ bsc, const float* __restrict__ bbi,
    const float* __restrict__ w8full, float* __restrict__ out)
{
  __shared__ unsigned char smem[131072];    // W1L 64K | W2L 32K | HS 8x4K
  short8* W1L = (short8*)smem;              // 4096 frags
  short8* W2L = (short8*)(smem + 65536);    // 2048 frags
  unsigned char* HS = smem + 98304 + (threadIdx.x >> 6) * 4096;

  const int g = blockIdx.x >> 8;            // fam 0..8
  const int tblk = blockIdx.x & 255;
  const int lane = threadIdx.x & 63;
  const int l15 = lane & 15, l4 = lane >> 4;
  const int tb = tblk * 128 + (threadIdx.x >> 6) * 16;
  const int type = (g < 2) ? 0 : (g < 4) ? 1 : (g < 6) ? 2 : (g < 8) ? 3 : 4;
  const int g2 = (g < 4) ? g : ((g == 8) ? 6 : g - 2);

  // ---- cooperative weight staging (issue all loads, then ds_writes) ----
  {
    const short8* s1 = (const short8*)(W1cat + g * 32768);
    short8 stg[12];
#pragma unroll
    for (int i = 0; i < 8; ++i) stg[i] = s1[threadIdx.x + i * 512];
    if (type != 2) {
      const short8* s2 = (const short8*)(W2cat + (size_t)g2 * 16384);
#pragma unroll
      for (int i = 0; i < 4; ++i) stg[8 + i] = s2[threadIdx.x + i * 512];
    }
#pragma unroll
    for (int i = 0; i < 8; ++i) W1L[threadIdx.x + i * 512] = stg[i];
    if (type != 2) {
#pragma unroll
      for (int i = 0; i < 4; ++i) W2L[threadIdx.x + i * 512] = stg[8 + i];
    }
  }
  // ---- A fragments (this wave's 16 tokens), f2bf identical to LDS path ----
  short8 A[8];
#pragma unroll
  for (int ks = 0; ks < 8; ++ks) {
    const float* xr = x + (size_t)(tb + l15) * 256 + ks * 32 + l4 * 8;
    float4 u = *(const float4*)xr, v = *(const float4*)(xr + 4);
    short8 a;
    a[0]=(short)f2bf(u.x); a[1]=(short)f2bf(u.y); a[2]=(short)f2bf(u.z); a[3]=(short)f2bf(u.w);
    a[4]=(short)f2bf(v.x); a[5]=(short)f2bf(v.y); a[6]=(short)f2bf(v.z); a[7]=(short)f2bf(v.w);
    A[ks] = a;
  }
  __syncthreads();                          // weights ready; waves free-run after

  f32x4 zero = {0.f, 0.f, 0.f, 0.f};
  const float RS = 1.0f / sqrtf(1.0f + 1e-5f);

  // ---- GEMM1 from LDS ----
  f32x4 acc[8];
#pragma unroll
  for (int nt = 0; nt < 8; ++nt) acc[nt] = zero;
#pragma unroll
  for (int ks = 0; ks < 8; ++ks)
#pragma unroll
    for (int nt = 0; nt < 8; ++nt)
      acc[nt] = MFMA16(A[ks], W1L[(ks * 8 + nt) * 64 + lane], acc[nt]);

  const float* b1 = b1cat + g * 128;

  if (type == 2) {                          // C: gelu -> masked atomic combine
#pragma unroll
    for (int r = 0; r < 4; ++r) {
      float wv_ = w8full[(size_t)(tb + l4 * 4 + r) * 8 + g];
#pragma unroll
      for (int nt = 0; nt < 8; ++nt) {
        float h = fgelu(acc[nt][r] + b1[nt * 16 + l15]);
        if (wv_ != 0.f)
          atomicAdd(&out[4194304 + (size_t)(tb + l4 * 4 + r) * 128 + nt * 16 + l15],
                    wv_ * h);
      }
    }
    return;
  }
  // activation
#pragma unroll
  for (int r = 0; r < 4; ++r)
#pragma unroll
    for (int nt = 0; nt < 8; ++nt) {
      float h = acc[nt][r] + b1[nt * 16 + l15];
      if (type == 0)      h = fmaxf(h, 0.f);
      else if (type == 1) {
        int col = (g - 2) * 128 + nt * 16 + l15;
        h = ftanh(h) * RS * bsc[col] + bbi[col];
      }
      else if (type == 3) h = fsilu(h);
      else                h = fmaxf(h, 0.f);            // S: relu
      acc[nt][r] = h;
    }
  if (type >= 3) {                          // layernorm (D: li=g-6, S: li=2), in-wave
    int li = (type == 4) ? 2 : (g - 6);
#pragma unroll
    for (int r = 0; r < 4; ++r) {
      float s1 = 0.f, s2 = 0.f;
#pragma unroll
      for (int nt = 0; nt < 8; ++nt) { float h = acc[nt][r]; s1 += h; s2 += h * h; }
      for (int m = 1; m <= 8; m <<= 1) { s1 += __shfl_xor(s1, m); s2 += __shfl_xor(s2, m); }
      float mu = s1 * (1.f / 128.f);
      float var = s2 * (1.f / 128.f) - mu * mu;
      float sc = __builtin_amdgcn_rsqf(var + 1e-5f);
#pragma unroll
      for (int nt = 0; nt < 8; ++nt) {
        int col = nt * 16 + l15;
        acc[nt][r] = (acc[nt][r] - mu) * sc * lng[li * 128 + col] + lnb[li * 128 + col];
      }
    }
  }
  // h tile -> LDS (bf16, swizzled, per-wave region), transpose back as A-frags
#pragma unroll
  for (int r = 0; r < 4; ++r) {
    int row = l4 * 4 + r;
#pragma unroll
    for (int nt = 0; nt < 8; ++nt) {
      int bytecol = (nt * 16 + l15) * 2;
      int addr = row * 256 + ((((bytecol >> 4) ^ (row & 7)) << 4) | (bytecol & 15));
      *(unsigned short*)(HS + addr) = f2bf(acc[nt][r]);
    }
  }
  short8 a2[4];
#pragma unroll
  for (int ks = 0; ks < 4; ++ks) {
    int ar = l15 * 256 + ((((ks * 4 + l4) ^ (l15 & 7)) << 4));
    a2[ks] = *(const short8*)(HS + ar);
  }
  // ---- GEMM2 from LDS ----
  f32x4 acc2[8];
#pragma unroll
  for (int nt = 0; nt < 8; ++nt) acc2[nt] = zero;
#pragma unroll
  for (int ks = 0; ks < 4; ++ks)
#pragma unroll
    for (int nt = 0; nt < 8; ++nt)
      acc2[nt] = MFMA16(a2[ks], W2L[(ks * 8 + nt) * 64 + lane], acc2[nt]);

  const float* b2 = b2cat + g2 * 128;
  if (type == 4) {                          // shared output: direct store
#pragma unroll
    for (int r = 0; r < 4; ++r) {
      int token = tb + l4 * 4 + r;
#pragma unroll
      for (int nt = 0; nt < 8; ++nt)
        out[(size_t)token * 128 + nt * 16 + l15] = acc2[nt][r] + b2[nt * 16 + l15];
    }
  } else {                                  // private: masked atomic combine
#pragma unroll
    for (int r = 0; r < 4; ++r) {
      float wv_ = w8full[(size_t)(tb + l4 * 4 + r) * 8 + g];
#pragma unroll
      for (int nt = 0; nt < 8; ++nt) {
        if (wv_ != 0.f)
          atomicAdd(&out[4194304 + (size_t)(tb + l4 * 4 + r) * 128 + nt * 16 + l15],
                    wv_ * (acc2[nt][r] + b2[nt * 16 + l15]));
      }
    }
  }
}

// ============== aux scalar ==============
__global__ void aux_kernel(const float* __restrict__ usage, float* __restrict__ out) {
  if (threadIdx.x == 0 && blockIdx.x == 0) {
    float a = 0.f;
    for (int e = 0; e < 8; ++e) {
      float u = usage[e] * (1.0f / 32768.0f);
      a += 0.125f * (logf(0.125f) - logf(u + 1e-10f));
    }
    out[8388608] = a * 0.125f;
  }
}

extern "C" void kernel_launch(void* const* d_in, const int* in_sizes, int n_in,
                              void* d_out, int out_size, void* d_ws, size_t ws_size,
                              hipStream_t stream) {
  (void)in_sizes; (void)n_in; (void)out_size; (void)ws_size;
  const float* x    = (const float*)d_in[0];
  const int*   mod  = (const int*)d_in[1];
  const float* A_W1 = (const float*)d_in[2];
  const float* A_b1 = (const float*)d_in[3];
  const float* A_W2 = (const float*)d_in[4];
  const float* A_b2 = (const float*)d_in[5];
  const float* B_W1 = (const float*)d_in[6];
  const float* B_b1 = (const float*)d_in[7];
  const float* B_g  = (const float*)d_in[8];
  const float* B_be = (const float*)d_in[9];
  const float* B_W2 = (const float*)d_in[10];
  const float* B_b2 = (const float*)d_in[11];
  const float* C_cw = (const float*)d_in[12];
  const float* C_cb = (const float*)d_in[13];
  const float* C_W  = (const float*)d_in[14];
  const float* C_b  = (const float*)d_in[15];
  const float* D_W1 = (const float*)d_in[16];
  const float* D_b1 = (const float*)d_in[17];
  const float* D_g  = (const float*)d_in[18];
  const float* D_be = (const float*)d_in[19];
  const float* D_W2 = (const float*)d_in[20];
  const float* D_b2 = (const float*)d_in[21];
  const float* S_W1 = (const float*)d_in[22];
  const float* S_b1 = (const float*)d_in[23];
  const float* S_g  = (const float*)d_in[24];
  const float* S_be = (const float*)d_in[25];
  const float* S_W2 = (const float*)d_in[26];
  const float* S_b2 = (const float*)d_in[27];
  const float* G_W1 = (const float*)d_in[28];
  const float* G_b1 = (const float*)d_in[29];
  const float* G_W2 = (const float*)d_in[30];
  const float* G_b2 = (const float*)d_in[31];

  char* ws = (char*)d_ws;
  unsigned short* W1cat = (unsigned short*)(ws + OFF_W1CAT);
  unsigned short* W2cat = (unsigned short*)(ws + OFF_W2CAT);
  float* W1T    = (float*)(ws + OFF_W1T);
  float* b1cat  = (float*)(ws + OFF_B1);
  float* b2cat  = (float*)(ws + OFF_B2);
  float* lng    = (float*)(ws + OFF_LNG);
  float* lnb    = (float*)(ws + OFF_LNB);
  float* bsc    = (float*)(ws + OFF_BSC);
  float* bbi    = (float*)(ws + OFF_BBI);
  float* usage  = (float*)(ws + OFF_USAGE);
  float* w8full = (float*)(ws + OFF_W8);
  float* out    = (float*)d_out;

  prep_kernel<<<1742, 256, 0, stream>>>(A_W1, A_b1, A_W2, A_b2, B_W1, B_b1, B_g, B_be,
      B_W2, B_b2, C_cw, C_cb, C_W, C_b, D_W1, D_b1, D_g, D_be, D_W2, D_b2,
      S_W1, S_b1, S_g, S_be, S_W2, S_b2, G_W1,
      W1cat, W2cat, W1T, b1cat, b2cat, lng, lnb, bsc, bbi, usage);
  prep2_kernel<<<4, 256, 0, stream>>>(C_cw, C_cb, C_W, b1cat);
  zero_kernel<<<2048, 256, 0, stream>>>(out);
  gate_np_kernel<<<512, 512, 0, stream>>>(x, mod, W1T, G_b1, G_W2, G_b2,
      w8full, usage);
  moe_kernel<<<2304, 512, 0, stream>>>(x, W1cat, W2cat, b1cat, b2cat, lng, lnb,
      bsc, bbi, w8full, out);
  aux_kernel<<<1, 64, 0, stream>>>(usage, out);
}

// Round 11
// 259.713 us; speedup vs baseline: 1.3716x; 1.2048x over previous
//
#include <hip/hip_runtime.h>
#include <hip/hip_bf16.h>
#include <math.h>

typedef __attribute__((ext_vector_type(8))) short short8;      // 8 bf16 (4 VGPRs)
typedef __attribute__((ext_vector_type(4))) float f32x4;       // MFMA acc
typedef __attribute__((ext_vector_type(4))) unsigned short us4;

#define MFMA16(a,b,c) __builtin_amdgcn_mfma_f32_16x16x32_bf16((a),(b),(c),0,0,0)

// ---------------- workspace layout (bytes) ----------------
// W1cat: bf16 fragment-ordered [9][ks=8][nt=8][lane=64][j=8]
// W2cat: bf16 fragment-ordered [7][ks=4][nt=8][lane=64][j=8]
#define OFF_W1CAT   0u
#define OFF_W2CAT   589824u
#define OFF_B1      950272u    // f32 [9][128]
#define OFF_B2      954880u    // f32 [7][128]
#define OFF_LNG     958464u    // f32 [3][128] (D0,D1,S gains)
#define OFF_LNB     960000u    // f32 [3][128]
#define OFF_BSC     961536u    // f32 [2][128] B_g
#define OFF_BBI     962560u    // f32 [2][128] B_be
#define OFF_USAGE   963584u    // f32 [8]
#define OFF_W8      963712u    // f32 [32768][8]
#define OFF_W1T     2012288u   // f32 [257][128]  gate W1 transposed

__device__ __forceinline__ unsigned short f2bf(float f) {
  union { float f; unsigned u; } v; v.f = f;
  return (unsigned short)((v.u + 0x7fffu + ((v.u >> 16) & 1u)) >> 16);
}
// ---- fast activations (v_exp/v_rcp based; |err| << bf16 quantization) ----
__device__ __forceinline__ float frcp(float x) { return __builtin_amdgcn_rcpf(x); }
__device__ __forceinline__ float ftanh(float x) {
  float ax = fabsf(x);
  float t = __expf(-2.f * ax);
  float r = (1.f - t) * frcp(1.f + t);
  return copysignf(r, x);
}
__device__ __forceinline__ float fsilu(float x) {
  return x * frcp(1.f + __expf(-x));
}
__device__ __forceinline__ float fgelu(float x) {   // exact-erf form, A&S 7.1.26
  float ax = fabsf(x) * 0.70710678118654752f;
  float t = frcp(fmaf(0.3275911f, ax, 1.f));
  float p = fmaf(t, 1.061405429f, -1.453152027f);
  p = fmaf(t, p, 1.421413741f);
  p = fmaf(t, p, -0.284496736f);
  p = fmaf(t, p, 0.254829592f);
  p *= t;
  float erfv = copysignf(fmaf(-p, __expf(-ax * ax), 1.f), x);
  return 0.5f * x * (1.f + erfv);
}

// ============== prep: pack weights (fragment-ordered), fold conv ==============
__global__ __launch_bounds__(256) void prep_kernel(
    const float* __restrict__ A_W1, const float* __restrict__ A_b1,
    const float* __restrict__ A_W2, const float* __restrict__ A_b2,
    const float* __restrict__ B_W1, const float* __restrict__ B_b1,
    const float* __restrict__ B_g,  const float* __restrict__ B_be,
    const float* __restrict__ B_W2, const float* __restrict__ B_b2,
    const float* __restrict__ C_cw, const float* __restrict__ C_cb,
    const float* __restrict__ C_W,  const float* __restrict__ C_b,
    const float* __restrict__ D_W1, const float* __restrict__ D_b1,
    const float* __restrict__ D_g,  const float* __restrict__ D_be,
    const float* __restrict__ D_W2, const float* __restrict__ D_b2,
    const float* __restrict__ S_W1, const float* __restrict__ S_b1,
    const float* __restrict__ S_g,  const float* __restrict__ S_be,
    const float* __restrict__ S_W2, const float* __restrict__ S_b2,
    const float* __restrict__ G_W1,
    unsigned short* __restrict__ W1cat, unsigned short* __restrict__ W2cat,
    float* __restrict__ W1T,
    float* __restrict__ b1cat, float* __restrict__ b2cat,
    float* __restrict__ lng, float* __restrict__ lnb,
    float* __restrict__ bsc, float* __restrict__ bbi,
    float* __restrict__ usage)
{
  int tid = blockIdx.x * 256 + threadIdx.x;
  if (tid < 294912) {                       // W1cat, fragment order
    int g = tid >> 15, rem = tid & 32767;
    int j = rem & 7, lane = (rem >> 3) & 63, nt = (rem >> 9) & 7, ks = rem >> 12;
    int p = nt * 16 + (lane & 15);
    int k = ks * 32 + (lane >> 4) * 8 + j;
    int src = p * 256 + k;
    float v;
    if (g < 2)      v = A_W1[g * 32768 + src];
    else if (g < 4) v = B_W1[(g - 2) * 32768 + src];
    else if (g < 6) {                       // Weff = conv folded into C_W
      int e = g - 4;
      v = 0.f;
      for (int c = 0; c < 4; ++c)
        for (int jj = 0; jj < 3; ++jj) {
          int h = k + 1 - jj;
          if (h >= 0 && h < 256)
            v += C_cw[e*12 + c*3 + jj] * C_W[e*131072 + p*1024 + c*256 + h];
        }
    }
    else if (g < 8) v = D_W1[(g - 6) * 32768 + src];
    else            v = S_W1[src];
    W1cat[tid] = f2bf(v);
    return;
  }
  tid -= 294912;
  if (tid < 114688) {                       // W2cat, fragment order
    int g = tid >> 14, rem = tid & 16383;
    int j = rem & 7, lane = (rem >> 3) & 63, nt = (rem >> 9) & 7, ks = rem >> 12;
    int p = nt * 16 + (lane & 15);
    int k = ks * 32 + (lane >> 4) * 8 + j;
    int src = p * 128 + k;
    float v;
    if (g < 2)      v = A_W2[g * 16384 + src];
    else if (g < 4) v = B_W2[(g - 2) * 16384 + src];
    else if (g < 6) v = D_W2[(g - 4) * 16384 + src];
    else            v = S_W2[src];
    W2cat[tid] = f2bf(v);
    return;
  }
  tid -= 114688;
  if (tid < 32896) {                        // W1T[k][o] = G_W1[o][k]
    int k = tid / 128, o = tid % 128;
    W1T[tid] = G_W1[o * 257 + k];
    return;
  }
  tid -= 32896;
  if (tid < 1152) {                         // b1cat (C fold added by prep2)
    int g = tid / 128, p = tid % 128;
    float v;
    if (g < 2)      v = A_b1[tid];
    else if (g < 4) v = B_b1[p + (g - 2) * 128];
    else if (g < 6) v = C_b[(g - 4) * 128 + p];
    else if (g < 8) v = D_b1[p + (g - 6) * 128];
    else            v = S_b1[p];
    b1cat[tid] = v;
    return;
  }
  tid -= 1152;
  if (tid < 896) {                          // b2cat
    int g = tid / 128, p = tid % 128;
    float v;
    if (g < 2)      v = A_b2[tid];
    else if (g < 4) v = B_b2[p + (g - 2) * 128];
    else if (g < 6) v = D_b2[p + (g - 4) * 128];
    else            v = S_b2[p];
    b2cat[tid] = v;
    return;
  }
  tid -= 896;
  if (tid < 768) {                          // LN gains/biases (D0,D1,S)
    if (tid < 384) {
      int j = tid / 128, p = tid % 128;
      lng[tid] = (j < 2) ? D_g[tid] : S_g[p];
    } else {
      int q = tid - 384; int j = q / 128, p = q % 128;
      lnb[q] = (j < 2) ? D_be[q] : S_be[p];
    }
    return;
  }
  tid -= 768;
  if (tid < 512) {                          // B scale/shift
    if (tid < 256) bsc[tid] = B_g[tid];
    else           bbi[tid - 256] = B_be[tid - 256];
    return;
  }
  tid -= 512;
  if (tid < 8) usage[tid] = 0.f;
}

// prep2: parallel conv-bias fold
__global__ __launch_bounds__(256) void prep2_kernel(
    const float* __restrict__ C_cw_unused, const float* __restrict__ C_cb,
    const float* __restrict__ C_W, float* __restrict__ b1cat)
{
  int tid = blockIdx.x * 256 + threadIdx.x;   // 1024 threads: (e,p,c)
  int e = tid >> 9, rem = tid & 511;
  int p = rem >> 2, c = rem & 3;
  const float4* row = (const float4*)(C_W + e*131072 + p*1024 + c*256);
  float s = 0.f;
  for (int q = 0; q < 64; ++q) {
    float4 v = row[q];
    s += v.x + v.y + v.z + v.w;
  }
  atomicAdd(&b1cat[(4 + e) * 128 + p], C_cb[e * 4 + c] * s);
}

// zero the private-output region (re-run every launch, before moe atomics)
__global__ __launch_bounds__(256) void zero_kernel(float* __restrict__ out) {
  int i = blockIdx.x * 256 + threadIdx.x;
  float4 z = {0.f, 0.f, 0.f, 0.f};
  float4* p = (float4*)(out + 4194304);
  p[i * 2] = z;
  p[i * 2 + 1] = z;
}

// ============== gate v3: token-on-lane, o-chains, exact np FMA order ==============
__global__ __launch_bounds__(512) void gate_np_kernel(
    const float* __restrict__ x, const int* __restrict__ modality,
    const float* __restrict__ W1T, const float* __restrict__ G_b1,
    const float* __restrict__ G_W2, const float* __restrict__ G_b2,
    float* __restrict__ w8full, float* __restrict__ usage)
{
  __shared__ unsigned char Ubuf[33024];     // xs [128][64] f32 (32KB) / ghs [64][129]
  __shared__ float ws2[8][132];
  __shared__ float lgs[64][9];
  float* xs  = (float*)Ubuf;
  float* ghs = (float*)Ubuf;
  const int tid = threadIdx.x;
  const int wv = __builtin_amdgcn_readfirstlane(tid >> 6);
  const int lane = tid & 63;
  const int tb = blockIdx.x * 64;
  const int o0 = wv * 16;
  const int t = lane;

  for (int i = tid; i < 1024; i += 512) ws2[i >> 7][i & 127] = G_W2[i];

  float acc[16];
#pragma unroll
  for (int j = 0; j < 16; ++j) acc[j] = 0.f;

  for (int p = 0; p < 2; ++p) {
    __syncthreads();                        // previous phase fully consumed
#pragma unroll
    for (int it = 0; it < 4; ++it) {
      int f = it * 512 + tid;               // float4 index in [64 rows][32 f4]
      int tt = f >> 5, c4 = f & 31;
      int kk = c4 * 4;
      const float4 v = *(const float4*)(x + (size_t)(tb + tt) * 256 + p * 128 + kk);
      int col = tt ^ (((kk >> 4) & 7) << 3);
      xs[(kk + 0) * 64 + col] = v.x;
      xs[(kk + 1) * 64 + col] = v.y;
      xs[(kk + 2) * 64 + col] = v.z;
      xs[(kk + 3) * 64 + col] = v.w;
    }
    __syncthreads();
    const float* wbase = W1T + (size_t)(p * 128) * 128 + o0;
    for (int kk = 0; kk < 128; ++kk) {
      float xv = xs[kk * 64 + (t ^ (((kk >> 4) & 7) << 3))];
      const float* wk = wbase + (size_t)kk * 128;
#pragma unroll
      for (int j = 0; j < 16; ++j)
        acc[j] = fmaf(xv, wk[j], acc[j]);   // exact sequential-k chain
    }
  }
  {
    float xv = (float)modality[tb + t];     // k = 256 (mod column)
    const float* wk = W1T + (size_t)256 * 128 + o0;
#pragma unroll
    for (int j = 0; j < 16; ++j)
      acc[j] = fmaf(xv, wk[j], acc[j]);
  }
  __syncthreads();                          // xs dead -> reuse as ghs
#pragma unroll
  for (int j = 0; j < 16; ++j)
    ghs[t * 129 + o0 + j] = (float)tanh((double)(acc[j] + G_b1[o0 + j]));
  __syncthreads();

  {
    int t2 = tid >> 3, e2 = tid & 7;
    float lg = 0.f;
    for (int o2 = 0; o2 < 128; ++o2)
      lg = fmaf(ghs[t2 * 129 + o2], ws2[e2][o2], lg);
    float s = (lg + G_b2[e2]) / 0.7f;       // f32 div
    lgs[t2][e2] = fminf(fmaxf(s, -10.f), 10.f);
  }
  __syncthreads();

  if (wv == 0) {                            // 64 tokens on 64 lanes
    int token = tb + lane;
    float v[8];
#pragma unroll
    for (int e = 0; e < 8; ++e) v[e] = lgs[lane][e];
    float tv[4]; int ti[4]; unsigned msk = 0;
    for (int kk = 0; kk < 4; ++kk) {        // ties -> lowest idx
      float best = -1e30f; int bi = 0;
      for (int e = 0; e < 8; ++e)
        if (!((msk >> e) & 1u) && v[e] > best) { best = v[e]; bi = e; }
      tv[kk] = best; ti[kk] = bi; msk |= 1u << bi;
    }
    float mx = tv[0], den = 0.f, wk4[4];
#pragma unroll
    for (int kk = 0; kk < 4; ++kk) { wk4[kk] = expf(tv[kk] - mx); den += wk4[kk]; }
#pragma unroll
    for (int e = 0; e < 8; ++e) {
      float val = 0.f;
#pragma unroll
      for (int kk = 0; kk < 4; ++kk) if (ti[kk] == e) val = wk4[kk] / den;
      w8full[(size_t)token * 8 + e] = val;
    }
    float uw[8];
    float dall = 0.f, pe[8];
#pragma unroll
    for (int e = 0; e < 8; ++e) { pe[e] = expf(v[e] - mx); dall += pe[e]; }
#pragma unroll
    for (int e = 0; e < 8; ++e) uw[e] = pe[e] / dall;
    for (int m = 1; m <= 32; m <<= 1)
#pragma unroll
      for (int e = 0; e < 8; ++e) uw[e] += __shfl_xor(uw[e], m);
    if (lane == 0)
      for (int e = 0; e < 8; ++e) atomicAdd(usage + e, uw[e]);
  }
}

// ============== moe v9: fam-per-block, 16 waves (4/SIMD), LDS weights ==============
// grid = 9 fams x 128 token-blocks. Block (1024 thr) stages fam W1(64K)+W2(32K)
// into LDS once for 256 tokens; 16 free-running waves (16 tokens each).
// Private fams: global f32 atomicAdd into pre-zeroed out; shared fam stores.
__global__ __launch_bounds__(1024, 4) void moe_kernel(
    const float* __restrict__ x,
    const unsigned short* __restrict__ W1cat, const unsigned short* __restrict__ W2cat,
    const float* __restrict__ b1cat, const float* __restrict__ b2cat,
    const float* __restrict__ lng, const float* __restrict__ lnb,
    const float* __restrict__ bsc, const float* __restrict__ bbi,
    const float* __restrict__ w8full, float* __restrict__ out)
{
  __shared__ unsigned char smem[163840];    // W1L 64K | W2L 32K | HS 16x4K
  short8* W1L = (short8*)smem;              // 4096 frags
  short8* W2L = (short8*)(smem + 65536);    // 2048 frags
  unsigned char* HS = smem + 98304 + (threadIdx.x >> 6) * 4096;

  const int g = blockIdx.x >> 7;            // fam 0..8
  const int tblk = blockIdx.x & 127;
  const int lane = threadIdx.x & 63;
  const int l15 = lane & 15, l4 = lane >> 4;
  const int tb = tblk * 256 + (threadIdx.x >> 6) * 16;
  const int type = (g < 2) ? 0 : (g < 4) ? 1 : (g < 6) ? 2 : (g < 8) ? 3 : 4;
  const int g2 = (g < 4) ? g : ((g == 8) ? 6 : g - 2);

  // ---- cooperative weight staging (issue all loads, then ds_writes) ----
  {
    const short8* s1 = (const short8*)(W1cat + g * 32768);
    short8 stg[6];
#pragma unroll
    for (int i = 0; i < 4; ++i) stg[i] = s1[threadIdx.x + i * 1024];
    if (type != 2) {
      const short8* s2 = (const short8*)(W2cat + (size_t)g2 * 16384);
#pragma unroll
      for (int i = 0; i < 2; ++i) stg[4 + i] = s2[threadIdx.x + i * 1024];
    }
#pragma unroll
    for (int i = 0; i < 4; ++i) W1L[threadIdx.x + i * 1024] = stg[i];
    if (type != 2) {
#pragma unroll
      for (int i = 0; i < 2; ++i) W2L[threadIdx.x + i * 1024] = stg[4 + i];
    }
  }
  // ---- A fragments (this wave's 16 tokens), f2bf identical to LDS path ----
  short8 A[8];
#pragma unroll
  for (int ks = 0; ks < 8; ++ks) {
    const float* xr = x + (size_t)(tb + l15) * 256 + ks * 32 + l4 * 8;
    float4 u = *(const float4*)xr, v = *(const float4*)(xr + 4);
    short8 a;
    a[0]=(short)f2bf(u.x); a[1]=(short)f2bf(u.y); a[2]=(short)f2bf(u.z); a[3]=(short)f2bf(u.w);
    a[4]=(short)f2bf(v.x); a[5]=(short)f2bf(v.y); a[6]=(short)f2bf(v.z); a[7]=(short)f2bf(v.w);
    A[ks] = a;
  }
  __syncthreads();                          // weights ready; waves free-run after

  f32x4 zero = {0.f, 0.f, 0.f, 0.f};
  const float RS = 1.0f / sqrtf(1.0f + 1e-5f);

  // ---- GEMM1 from LDS ----
  f32x4 acc[8];
#pragma unroll
  for (int nt = 0; nt < 8; ++nt) acc[nt] = zero;
#pragma unroll
  for (int ks = 0; ks < 8; ++ks)
#pragma unroll
    for (int nt = 0; nt < 8; ++nt)
      acc[nt] = MFMA16(A[ks], W1L[(ks * 8 + nt) * 64 + lane], acc[nt]);

  const float* b1 = b1cat + g * 128;

  if (type == 2) {                          // C: gelu -> masked atomic combine
#pragma unroll
    for (int r = 0; r < 4; ++r) {
      float wv_ = w8full[(size_t)(tb + l4 * 4 + r) * 8 + g];
#pragma unroll
      for (int nt = 0; nt < 8; ++nt) {
        float h = fgelu(acc[nt][r] + b1[nt * 16 + l15]);
        if (wv_ != 0.f)
          atomicAdd(&out[4194304 + (size_t)(tb + l4 * 4 + r) * 128 + nt * 16 + l15],
                    wv_ * h);
      }
    }
    return;
  }
  // activation
#pragma unroll
  for (int r = 0; r < 4; ++r)
#pragma unroll
    for (int nt = 0; nt < 8; ++nt) {
      float h = acc[nt][r] + b1[nt * 16 + l15];
      if (type == 0)      h = fmaxf(h, 0.f);
      else if (type == 1) {
        int col = (g - 2) * 128 + nt * 16 + l15;
        h = ftanh(h) * RS * bsc[col] + bbi[col];
      }
      else if (type == 3) h = fsilu(h);
      else                h = fmaxf(h, 0.f);            // S: relu
      acc[nt][r] = h;
    }
  if (type >= 3) {                          // layernorm (D: li=g-6, S: li=2), in-wave
    int li = (type == 4) ? 2 : (g - 6);
#pragma unroll
    for (int r = 0; r < 4; ++r) {
      float s1 = 0.f, s2 = 0.f;
#pragma unroll
      for (int nt = 0; nt < 8; ++nt) { float h = acc[nt][r]; s1 += h; s2 += h * h; }
      for (int m = 1; m <= 8; m <<= 1) { s1 += __shfl_xor(s1, m); s2 += __shfl_xor(s2, m); }
      float mu = s1 * (1.f / 128.f);
      float var = s2 * (1.f / 128.f) - mu * mu;
      float sc = __builtin_amdgcn_rsqf(var + 1e-5f);
#pragma unroll
      for (int nt = 0; nt < 8; ++nt) {
        int col = nt * 16 + l15;
        acc[nt][r] = (acc[nt][r] - mu) * sc * lng[li * 128 + col] + lnb[li * 128 + col];
      }
    }
  }
  // h tile -> LDS (bf16, swizzled, per-wave region), transpose back as A-frags
#pragma unroll
  for (int r = 0; r < 4; ++r) {
    int row = l4 * 4 + r;
#pragma unroll
    for (int nt = 0; nt < 8; ++nt) {
      int bytecol = (nt * 16 + l15) * 2;
      int addr = row * 256 + ((((bytecol >> 4) ^ (row & 7)) << 4) | (bytecol & 15));
      *(unsigned short*)(HS + addr) = f2bf(acc[nt][r]);
    }
  }
  short8 a2[4];
#pragma unroll
  for (int ks = 0; ks < 4; ++ks) {
    int ar = l15 * 256 + ((((ks * 4 + l4) ^ (l15 & 7)) << 4));
    a2[ks] = *(const short8*)(HS + ar);
  }
  // ---- GEMM2 from LDS ----
  f32x4 acc2[8];
#pragma unroll
  for (int nt = 0; nt < 8; ++nt) acc2[nt] = zero;
#pragma unroll
  for (int ks = 0; ks < 4; ++ks)
#pragma unroll
    for (int nt = 0; nt < 8; ++nt)
      acc2[nt] = MFMA16(a2[ks], W2L[(ks * 8 + nt) * 64 + lane], acc2[nt]);

  const float* b2 = b2cat + g2 * 128;
  if (type == 4) {                          // shared output: direct store
#pragma unroll
    for (int r = 0; r < 4; ++r) {
      int token = tb + l4 * 4 + r;
#pragma unroll
      for (int nt = 0; nt < 8; ++nt)
        out[(size_t)token * 128 + nt * 16 + l15] = acc2[nt][r] + b2[nt * 16 + l15];
    }
  } else {                                  // private: masked atomic combine
#pragma unroll
    for (int r = 0; r < 4; ++r) {
      float wv_ = w8full[(size_t)(tb + l4 * 4 + r) * 8 + g];
#pragma unroll
      for (int nt = 0; nt < 8; ++nt) {
        if (wv_ != 0.f)
          atomicAdd(&out[4194304 + (size_t)(tb + l4 * 4 + r) * 128 + nt * 16 + l15],
                    wv_ * (acc2[nt][r] + b2[nt * 16 + l15]));
      }
    }
  }
}

// ============== aux scalar ==============
__global__ void aux_kernel(const float* __restrict__ usage, float* __restrict__ out) {
  if (threadIdx.x == 0 && blockIdx.x == 0) {
    float a = 0.f;
    for (int e = 0; e < 8; ++e) {
      float u = usage[e] * (1.0f / 32768.0f);
      a += 0.125f * (logf(0.125f) - logf(u + 1e-10f));
    }
    out[8388608] = a * 0.125f;
  }
}

extern "C" void kernel_launch(void* const* d_in, const int* in_sizes, int n_in,
                              void* d_out, int out_size, void* d_ws, size_t ws_size,
                              hipStream_t stream) {
  (void)in_sizes; (void)n_in; (void)out_size; (void)ws_size;
  const float* x    = (const float*)d_in[0];
  const int*   mod  = (const int*)d_in[1];
  const float* A_W1 = (const float*)d_in[2];
  const float* A_b1 = (const float*)d_in[3];
  const float* A_W2 = (const float*)d_in[4];
  const float* A_b2 = (const float*)d_in[5];
  const float* B_W1 = (const float*)d_in[6];
  const float* B_b1 = (const float*)d_in[7];
  const float* B_g  = (const float*)d_in[8];
  const float* B_be = (const float*)d_in[9];
  const float* B_W2 = (const float*)d_in[10];
  const float* B_b2 = (const float*)d_in[11];
  const float* C_cw = (const float*)d_in[12];
  const float* C_cb = (const float*)d_in[13];
  const float* C_W  = (const float*)d_in[14];
  const float* C_b  = (const float*)d_in[15];
  const float* D_W1 = (const float*)d_in[16];
  const float* D_b1 = (const float*)d_in[17];
  const float* D_g  = (const float*)d_in[18];
  const float* D_be = (const float*)d_in[19];
  const float* D_W2 = (const float*)d_in[20];
  const float* D_b2 = (const float*)d_in[21];
  const float* S_W1 = (const float*)d_in[22];
  const float* S_b1 = (const float*)d_in[23];
  const float* S_g  = (const float*)d_in[24];
  const float* S_be = (const float*)d_in[25];
  const float* S_W2 = (const float*)d_in[26];
  const float* S_b2 = (const float*)d_in[27];
  const float* G_W1 = (const float*)d_in[28];
  const float* G_b1 = (const float*)d_in[29];
  const float* G_W2 = (const float*)d_in[30];
  const float* G_b2 = (const float*)d_in[31];

  char* ws = (char*)d_ws;
  unsigned short* W1cat = (unsigned short*)(ws + OFF_W1CAT);
  unsigned short* W2cat = (unsigned short*)(ws + OFF_W2CAT);
  float* W1T    = (float*)(ws + OFF_W1T);
  float* b1cat  = (float*)(ws + OFF_B1);
  float* b2cat  = (float*)(ws + OFF_B2);
  float* lng    = (float*)(ws + OFF_LNG);
  float* lnb    = (float*)(ws + OFF_LNB);
  float* bsc    = (float*)(ws + OFF_BSC);
  float* bbi    = (float*)(ws + OFF_BBI);
  float* usage  = (float*)(ws + OFF_USAGE);
  float* w8full = (float*)(ws + OFF_W8);
  float* out    = (float*)d_out;

  prep_kernel<<<1742, 256, 0, stream>>>(A_W1, A_b1, A_W2, A_b2, B_W1, B_b1, B_g, B_be,
      B_W2, B_b2, C_cw, C_cb, C_W, C_b, D_W1, D_b1, D_g, D_be, D_W2, D_b2,
      S_W1, S_b1, S_g, S_be, S_W2, S_b2, G_W1,
      W1cat, W2cat, W1T, b1cat, b2cat, lng, lnb, bsc, bbi, usage);
  prep2_kernel<<<4, 256, 0, stream>>>(C_cw, C_cb, C_W, b1cat);
  zero_kernel<<<2048, 256, 0, stream>>>(out);
  gate_np_kernel<<<512, 512, 0, stream>>>(x, mod, W1T, G_b1, G_W2, G_b2,
      w8full, usage);
  moe_kernel<<<1152, 1024, 0, stream>>>(x, W1cat, W2cat, b1cat, b2cat, lng, lnb,
      bsc, bbi, w8full, out);
  aux_kernel<<<1, 64, 0, stream>>>(usage, out);
}

// Round 12
// 220.649 us; speedup vs baseline: 1.6145x; 1.1770x over previous
//
#include <hip/hip_runtime.h>
#include <hip/hip_bf16.h>
#include <math.h>

typedef __attribute__((ext_vector_type(8))) short short8;      // 8 bf16 (4 VGPRs)
typedef __attribute__((ext_vector_type(4))) float f32x4;       // MFMA acc
typedef __attribute__((ext_vector_type(4))) unsigned short us4;

#define MFMA16(a,b,c) __builtin_amdgcn_mfma_f32_16x16x32_bf16((a),(b),(c),0,0,0)

// ---------------- workspace layout (bytes) ----------------
// W1cat: bf16 fragment-ordered [9][ks=8][nt=8][lane=64][j=8]
// W2cat: bf16 fragment-ordered [7][ks=4][nt=8][lane=64][j=8]
#define OFF_W1CAT   0u
#define OFF_W2CAT   589824u
#define OFF_B1      950272u    // f32 [9][128]
#define OFF_B2      954880u    // f32 [7][128]
#define OFF_LNG     958464u    // f32 [3][128] (D0,D1,S gains)
#define OFF_LNB     960000u    // f32 [3][128]
#define OFF_BSC     961536u    // f32 [2][128] B_g
#define OFF_BBI     962560u    // f32 [2][128] B_be
#define OFF_USAGE   963584u    // f32 [8]
#define OFF_W8      963712u    // f32 [32768][8]
#define OFF_W1T     2012288u   // f32 [257][128]  gate W1 transposed

__device__ __forceinline__ unsigned short f2bf(float f) {
  union { float f; unsigned u; } v; v.f = f;
  return (unsigned short)((v.u + 0x7fffu + ((v.u >> 16) & 1u)) >> 16);
}
// ---- fast activations (v_exp/v_rcp based; |err| << bf16 quantization) ----
__device__ __forceinline__ float frcp(float x) { return __builtin_amdgcn_rcpf(x); }
__device__ __forceinline__ float ftanh(float x) {
  float ax = fabsf(x);
  float t = __expf(-2.f * ax);
  float r = (1.f - t) * frcp(1.f + t);
  return copysignf(r, x);
}
__device__ __forceinline__ float fsilu(float x) {
  return x * frcp(1.f + __expf(-x));
}
__device__ __forceinline__ float fgelu(float x) {   // exact-erf form, A&S 7.1.26
  float ax = fabsf(x) * 0.70710678118654752f;
  float t = frcp(fmaf(0.3275911f, ax, 1.f));
  float p = fmaf(t, 1.061405429f, -1.453152027f);
  p = fmaf(t, p, 1.421413741f);
  p = fmaf(t, p, -0.284496736f);
  p = fmaf(t, p, 0.254829592f);
  p *= t;
  float erfv = copysignf(fmaf(-p, __expf(-ax * ax), 1.f), x);
  return 0.5f * x * (1.f + erfv);
}

// ============== prep: pack weights (fragment-ordered), fold conv ==============
__global__ __launch_bounds__(256) void prep_kernel(
    const float* __restrict__ A_W1, const float* __restrict__ A_b1,
    const float* __restrict__ A_W2, const float* __restrict__ A_b2,
    const float* __restrict__ B_W1, const float* __restrict__ B_b1,
    const float* __restrict__ B_g,  const float* __restrict__ B_be,
    const float* __restrict__ B_W2, const float* __restrict__ B_b2,
    const float* __restrict__ C_cw, const float* __restrict__ C_cb,
    const float* __restrict__ C_W,  const float* __restrict__ C_b,
    const float* __restrict__ D_W1, const float* __restrict__ D_b1,
    const float* __restrict__ D_g,  const float* __restrict__ D_be,
    const float* __restrict__ D_W2, const float* __restrict__ D_b2,
    const float* __restrict__ S_W1, const float* __restrict__ S_b1,
    const float* __restrict__ S_g,  const float* __restrict__ S_be,
    const float* __restrict__ S_W2, const float* __restrict__ S_b2,
    const float* __restrict__ G_W1,
    unsigned short* __restrict__ W1cat, unsigned short* __restrict__ W2cat,
    float* __restrict__ W1T,
    float* __restrict__ b1cat, float* __restrict__ b2cat,
    float* __restrict__ lng, float* __restrict__ lnb,
    float* __restrict__ bsc, float* __restrict__ bbi,
    float* __restrict__ usage)
{
  int tid = blockIdx.x * 256 + threadIdx.x;
  if (tid < 294912) {                       // W1cat, fragment order
    int g = tid >> 15, rem = tid & 32767;
    int j = rem & 7, lane = (rem >> 3) & 63, nt = (rem >> 9) & 7, ks = rem >> 12;
    int p = nt * 16 + (lane & 15);
    int k = ks * 32 + (lane >> 4) * 8 + j;
    int src = p * 256 + k;
    float v;
    if (g < 2)      v = A_W1[g * 32768 + src];
    else if (g < 4) v = B_W1[(g - 2) * 32768 + src];
    else if (g < 6) {                       // Weff = conv folded into C_W
      int e = g - 4;
      v = 0.f;
      for (int c = 0; c < 4; ++c)
        for (int jj = 0; jj < 3; ++jj) {
          int h = k + 1 - jj;
          if (h >= 0 && h < 256)
            v += C_cw[e*12 + c*3 + jj] * C_W[e*131072 + p*1024 + c*256 + h];
        }
    }
    else if (g < 8) v = D_W1[(g - 6) * 32768 + src];
    else            v = S_W1[src];
    W1cat[tid] = f2bf(v);
    return;
  }
  tid -= 294912;
  if (tid < 114688) {                       // W2cat, fragment order
    int g = tid >> 14, rem = tid & 16383;
    int j = rem & 7, lane = (rem >> 3) & 63, nt = (rem >> 9) & 7, ks = rem >> 12;
    int p = nt * 16 + (lane & 15);
    int k = ks * 32 + (lane >> 4) * 8 + j;
    int src = p * 128 + k;
    float v;
    if (g < 2)      v = A_W2[g * 16384 + src];
    else if (g < 4) v = B_W2[(g - 2) * 16384 + src];
    else if (g < 6) v = D_W2[(g - 4) * 16384 + src];
    else            v = S_W2[src];
    W2cat[tid] = f2bf(v);
    return;
  }
  tid -= 114688;
  if (tid < 32896) {                        // W1T[k][o] = G_W1[o][k]
    int k = tid / 128, o = tid % 128;
    W1T[tid] = G_W1[o * 257 + k];
    return;
  }
  tid -= 32896;
  if (tid < 1152) {                         // b1cat (C fold added by prep2)
    int g = tid / 128, p = tid % 128;
    float v;
    if (g < 2)      v = A_b1[tid];
    else if (g < 4) v = B_b1[p + (g - 2) * 128];
    else if (g < 6) v = C_b[(g - 4) * 128 + p];
    else if (g < 8) v = D_b1[p + (g - 6) * 128];
    else            v = S_b1[p];
    b1cat[tid] = v;
    return;
  }
  tid -= 1152;
  if (tid < 896) {                          // b2cat
    int g = tid / 128, p = tid % 128;
    float v;
    if (g < 2)      v = A_b2[tid];
    else if (g < 4) v = B_b2[p + (g - 2) * 128];
    else if (g < 6) v = D_b2[p + (g - 4) * 128];
    else            v = S_b2[p];
    b2cat[tid] = v;
    return;
  }
  tid -= 896;
  if (tid < 768) {                          // LN gains/biases (D0,D1,S)
    if (tid < 384) {
      int j = tid / 128, p = tid % 128;
      lng[tid] = (j < 2) ? D_g[tid] : S_g[p];
    } else {
      int q = tid - 384; int j = q / 128, p = q % 128;
      lnb[q] = (j < 2) ? D_be[q] : S_be[p];
    }
    return;
  }
  tid -= 768;
  if (tid < 512) {                          // B scale/shift
    if (tid < 256) bsc[tid] = B_g[tid];
    else           bbi[tid - 256] = B_be[tid - 256];
    return;
  }
  tid -= 512;
  if (tid < 8) usage[tid] = 0.f;
}

// prep2: parallel conv-bias fold
__global__ __launch_bounds__(256) void prep2_kernel(
    const float* __restrict__ C_cw_unused, const float* __restrict__ C_cb,
    const float* __restrict__ C_W, float* __restrict__ b1cat)
{
  int tid = blockIdx.x * 256 + threadIdx.x;   // 1024 threads: (e,p,c)
  int e = tid >> 9, rem = tid & 511;
  int p = rem >> 2, c = rem & 3;
  const float4* row = (const float4*)(C_W + e*131072 + p*1024 + c*256);
  float s = 0.f;
  for (int q = 0; q < 64; ++q) {
    float4 v = row[q];
    s += v.x + v.y + v.z + v.w;
  }
  atomicAdd(&b1cat[(4 + e) * 128 + p], C_cb[e * 4 + c] * s);
}

// ============== gate v3: token-on-lane, o-chains, exact np FMA order ==============
__global__ __launch_bounds__(512) void gate_np_kernel(
    const float* __restrict__ x, const int* __restrict__ modality,
    const float* __restrict__ W1T, const float* __restrict__ G_b1,
    const float* __restrict__ G_W2, const float* __restrict__ G_b2,
    float* __restrict__ w8full, float* __restrict__ usage)
{
  __shared__ unsigned char Ubuf[33024];     // xs [128][64] f32 (32KB) / ghs [64][129]
  __shared__ float ws2[8][132];
  __shared__ float lgs[64][9];
  float* xs  = (float*)Ubuf;
  float* ghs = (float*)Ubuf;
  const int tid = threadIdx.x;
  const int wv = __builtin_amdgcn_readfirstlane(tid >> 6);
  const int lane = tid & 63;
  const int tb = blockIdx.x * 64;
  const int o0 = wv * 16;
  const int t = lane;

  for (int i = tid; i < 1024; i += 512) ws2[i >> 7][i & 127] = G_W2[i];

  float acc[16];
#pragma unroll
  for (int j = 0; j < 16; ++j) acc[j] = 0.f;

  for (int p = 0; p < 2; ++p) {
    __syncthreads();                        // previous phase fully consumed
#pragma unroll
    for (int it = 0; it < 4; ++it) {
      int f = it * 512 + tid;               // float4 index in [64 rows][32 f4]
      int tt = f >> 5, c4 = f & 31;
      int kk = c4 * 4;
      const float4 v = *(const float4*)(x + (size_t)(tb + tt) * 256 + p * 128 + kk);
      int col = tt ^ (((kk >> 4) & 7) << 3);
      xs[(kk + 0) * 64 + col] = v.x;
      xs[(kk + 1) * 64 + col] = v.y;
      xs[(kk + 2) * 64 + col] = v.z;
      xs[(kk + 3) * 64 + col] = v.w;
    }
    __syncthreads();
    const float* wbase = W1T + (size_t)(p * 128) * 128 + o0;
    for (int kk = 0; kk < 128; ++kk) {
      float xv = xs[kk * 64 + (t ^ (((kk >> 4) & 7) << 3))];
      const float* wk = wbase + (size_t)kk * 128;
#pragma unroll
      for (int j = 0; j < 16; ++j)
        acc[j] = fmaf(xv, wk[j], acc[j]);   // exact sequential-k chain
    }
  }
  {
    float xv = (float)modality[tb + t];     // k = 256 (mod column)
    const float* wk = W1T + (size_t)256 * 128 + o0;
#pragma unroll
    for (int j = 0; j < 16; ++j)
      acc[j] = fmaf(xv, wk[j], acc[j]);
  }
  __syncthreads();                          // xs dead -> reuse as ghs
#pragma unroll
  for (int j = 0; j < 16; ++j)
    ghs[t * 129 + o0 + j] = (float)tanh((double)(acc[j] + G_b1[o0 + j]));
  __syncthreads();

  {
    int t2 = tid >> 3, e2 = tid & 7;
    float lg = 0.f;
    for (int o2 = 0; o2 < 128; ++o2)
      lg = fmaf(ghs[t2 * 129 + o2], ws2[e2][o2], lg);
    float s = (lg + G_b2[e2]) / 0.7f;       // f32 div
    lgs[t2][e2] = fminf(fmaxf(s, -10.f), 10.f);
  }
  __syncthreads();

  if (wv == 0) {                            // 64 tokens on 64 lanes
    int token = tb + lane;
    float v[8];
#pragma unroll
    for (int e = 0; e < 8; ++e) v[e] = lgs[lane][e];
    float tv[4]; int ti[4]; unsigned msk = 0;
    for (int kk = 0; kk < 4; ++kk) {        // ties -> lowest idx
      float best = -1e30f; int bi = 0;
      for (int e = 0; e < 8; ++e)
        if (!((msk >> e) & 1u) && v[e] > best) { best = v[e]; bi = e; }
      tv[kk] = best; ti[kk] = bi; msk |= 1u << bi;
    }
    float mx = tv[0], den = 0.f, wk4[4];
#pragma unroll
    for (int kk = 0; kk < 4; ++kk) { wk4[kk] = expf(tv[kk] - mx); den += wk4[kk]; }
#pragma unroll
    for (int e = 0; e < 8; ++e) {
      float val = 0.f;
#pragma unroll
      for (int kk = 0; kk < 4; ++kk) if (ti[kk] == e) val = wk4[kk] / den;
      w8full[(size_t)token * 8 + e] = val;
    }
    float uw[8];
    float dall = 0.f, pe[8];
#pragma unroll
    for (int e = 0; e < 8; ++e) { pe[e] = expf(v[e] - mx); dall += pe[e]; }
#pragma unroll
    for (int e = 0; e < 8; ++e) uw[e] = pe[e] / dall;
    for (int m = 1; m <= 32; m <<= 1)
#pragma unroll
      for (int e = 0; e < 8; ++e) uw[e] += __shfl_xor(uw[e], m);
    if (lane == 0)
      for (int e = 0; e < 8; ++e) atomicAdd(usage + e, uw[e]);
  }
}

// ============== moe v10: token-block/block, fam loop, LDS weights, reg combine ==============
// grid = 256 blocks x 128 tokens (1 block/CU). Loop fams 0..8: stage fam weights
// to LDS (next fam's loads prefetched into registers during compute), GEMM1 ->
// epilogue -> GEMM2 per wave (16 tokens), combine in pacc REGISTERS. No atomics.
__global__ __launch_bounds__(512, 2) void moe_kernel(
    const float* __restrict__ x,
    const unsigned short* __restrict__ W1cat, const unsigned short* __restrict__ W2cat,
    const float* __restrict__ b1cat, const float* __restrict__ b2cat,
    const float* __restrict__ lng, const float* __restrict__ lnb,
    const float* __restrict__ bsc, const float* __restrict__ bbi,
    const float* __restrict__ w8full, float* __restrict__ out)
{
  __shared__ unsigned char smem[131072];    // W1L 64K | W2L 32K | HS 8x4K
  short8* W1L = (short8*)smem;              // 4096 frags
  short8* W2L = (short8*)(smem + 65536);    // 2048 frags
  unsigned char* HS = smem + 98304 + (threadIdx.x >> 6) * 4096;

  const int tid = threadIdx.x;
  const int wv = tid >> 6, lane = tid & 63;
  const int l15 = lane & 15, l4 = lane >> 4;
  const int tb = blockIdx.x * 128 + wv * 16;
  const short8* W1f = (const short8*)W1cat;
  const short8* W2f = (const short8*)W2cat;

  // ---- A fragments (this wave's 16 tokens), f2bf identical to earlier rounds ----
  short8 A[8];
#pragma unroll
  for (int ks = 0; ks < 8; ++ks) {
    const float* xr = x + (size_t)(tb + l15) * 256 + ks * 32 + l4 * 8;
    float4 u = *(const float4*)xr, v = *(const float4*)(xr + 4);
    short8 a;
    a[0]=(short)f2bf(u.x); a[1]=(short)f2bf(u.y); a[2]=(short)f2bf(u.z); a[3]=(short)f2bf(u.w);
    a[4]=(short)f2bf(v.x); a[5]=(short)f2bf(v.y); a[6]=(short)f2bf(v.z); a[7]=(short)f2bf(v.w);
    A[ks] = a;
  }

  f32x4 zero = {0.f, 0.f, 0.f, 0.f};
  f32x4 pacc[8];
#pragma unroll
  for (int nt = 0; nt < 8; ++nt) pacc[nt] = zero;
  const float RS = 1.0f / sqrtf(1.0f + 1e-5f);

  // prologue: load fam-0 weights into registers
  short8 stg[12];
#pragma unroll
  for (int i = 0; i < 8; ++i) stg[i] = W1f[tid + i * 512];
#pragma unroll
  for (int i = 0; i < 4; ++i) stg[8 + i] = W2f[tid + i * 512];

  for (int g = 0; g < 9; ++g) {
    const int type = (g < 2) ? 0 : (g < 4) ? 1 : (g < 6) ? 2 : (g < 8) ? 3 : 4;
    const int g2 = (g < 4) ? g : ((g == 8) ? 6 : g - 2);

    __syncthreads();                        // prev fam's compute done with LDS W
#pragma unroll
    for (int i = 0; i < 8; ++i) W1L[tid + i * 512] = stg[i];
#pragma unroll
    for (int i = 0; i < 4; ++i) W2L[tid + i * 512] = stg[8 + i];
    if (g < 8) {                            // prefetch next fam during compute
      int gn = g + 1;
      int g2n = (gn < 4) ? gn : ((gn == 8) ? 6 : gn - 2);
#pragma unroll
      for (int i = 0; i < 8; ++i) stg[i] = W1f[(size_t)gn * 4096 + tid + i * 512];
#pragma unroll
      for (int i = 0; i < 4; ++i) stg[8 + i] = W2f[(size_t)g2n * 2048 + tid + i * 512];
    }
    __syncthreads();                        // staged weights visible

    // ---- GEMM1 from LDS ----
    f32x4 acc[8];
#pragma unroll
    for (int nt = 0; nt < 8; ++nt) acc[nt] = zero;
#pragma unroll
    for (int ks = 0; ks < 8; ++ks)
#pragma unroll
      for (int nt = 0; nt < 8; ++nt)
        acc[nt] = MFMA16(A[ks], W1L[(ks * 8 + nt) * 64 + lane], acc[nt]);

    const float* b1 = b1cat + g * 128;

    if (type == 2) {                        // C: gelu -> weighted reg combine
#pragma unroll
      for (int r = 0; r < 4; ++r) {
        float wv_ = w8full[(size_t)(tb + l4 * 4 + r) * 8 + g];
#pragma unroll
        for (int nt = 0; nt < 8; ++nt) {
          float h = fgelu(acc[nt][r] + b1[nt * 16 + l15]);
          pacc[nt][r] += wv_ * h;
        }
      }
      continue;
    }
    // activation
#pragma unroll
    for (int r = 0; r < 4; ++r)
#pragma unroll
      for (int nt = 0; nt < 8; ++nt) {
        float h = acc[nt][r] + b1[nt * 16 + l15];
        if (type == 0)      h = fmaxf(h, 0.f);
        else if (type == 1) {
          int col = (g - 2) * 128 + nt * 16 + l15;
          h = ftanh(h) * RS * bsc[col] + bbi[col];
        }
        else if (type == 3) h = fsilu(h);
        else                h = fmaxf(h, 0.f);            // S: relu
        acc[nt][r] = h;
      }
    if (type >= 3) {                        // layernorm (D: li=g-6, S: li=2), in-wave
      int li = (type == 4) ? 2 : (g - 6);
#pragma unroll
      for (int r = 0; r < 4; ++r) {
        float s1 = 0.f, s2 = 0.f;
#pragma unroll
        for (int nt = 0; nt < 8; ++nt) { float h = acc[nt][r]; s1 += h; s2 += h * h; }
        for (int m = 1; m <= 8; m <<= 1) { s1 += __shfl_xor(s1, m); s2 += __shfl_xor(s2, m); }
        float mu = s1 * (1.f / 128.f);
        float var = s2 * (1.f / 128.f) - mu * mu;
        float sc = __builtin_amdgcn_rsqf(var + 1e-5f);
#pragma unroll
        for (int nt = 0; nt < 8; ++nt) {
          int col = nt * 16 + l15;
          acc[nt][r] = (acc[nt][r] - mu) * sc * lng[li * 128 + col] + lnb[li * 128 + col];
        }
      }
    }
    // h tile -> LDS (bf16, swizzled, per-wave region), transpose back as A-frags
#pragma unroll
    for (int r = 0; r < 4; ++r) {
      int row = l4 * 4 + r;
#pragma unroll
      for (int nt = 0; nt < 8; ++nt) {
        int bytecol = (nt * 16 + l15) * 2;
        int addr = row * 256 + ((((bytecol >> 4) ^ (row & 7)) << 4) | (bytecol & 15));
        *(unsigned short*)(HS + addr) = f2bf(acc[nt][r]);
      }
    }
    short8 a2[4];
#pragma unroll
    for (int ks = 0; ks < 4; ++ks) {
      int ar = l15 * 256 + ((((ks * 4 + l4) ^ (l15 & 7)) << 4));
      a2[ks] = *(const short8*)(HS + ar);
    }
    // ---- GEMM2 from LDS ----
    f32x4 acc2[8];
#pragma unroll
    for (int nt = 0; nt < 8; ++nt) acc2[nt] = zero;
#pragma unroll
    for (int ks = 0; ks < 4; ++ks)
#pragma unroll
      for (int nt = 0; nt < 8; ++nt)
        acc2[nt] = MFMA16(a2[ks], W2L[(ks * 8 + nt) * 64 + lane], acc2[nt]);

    const float* b2 = b2cat + g2 * 128;
    if (type == 4) {                        // shared output: direct store
#pragma unroll
      for (int r = 0; r < 4; ++r) {
        int token = tb + l4 * 4 + r;
#pragma unroll
        for (int nt = 0; nt < 8; ++nt)
          out[(size_t)token * 128 + nt * 16 + l15] = acc2[nt][r] + b2[nt * 16 + l15];
      }
    } else {                                // private: weighted reg combine
#pragma unroll
      for (int r = 0; r < 4; ++r) {
        float wv_ = w8full[(size_t)(tb + l4 * 4 + r) * 8 + g];
#pragma unroll
        for (int nt = 0; nt < 8; ++nt)
          pacc[nt][r] += wv_ * (acc2[nt][r] + b2[nt * 16 + l15]);
      }
    }
  }
  // private output: one plain store per element
#pragma unroll
  for (int r = 0; r < 4; ++r) {
    int token = tb + l4 * 4 + r;
#pragma unroll
    for (int nt = 0; nt < 8; ++nt)
      out[4194304 + (size_t)token * 128 + nt * 16 + l15] = pacc[nt][r];
  }
}

// ============== aux scalar ==============
__global__ void aux_kernel(const float* __restrict__ usage, float* __restrict__ out) {
  if (threadIdx.x == 0 && blockIdx.x == 0) {
    float a = 0.f;
    for (int e = 0; e < 8; ++e) {
      float u = usage[e] * (1.0f / 32768.0f);
      a += 0.125f * (logf(0.125f) - logf(u + 1e-10f));
    }
    out[8388608] = a * 0.125f;
  }
}

extern "C" void kernel_launch(void* const* d_in, const int* in_sizes, int n_in,
                              void* d_out, int out_size, void* d_ws, size_t ws_size,
                              hipStream_t stream) {
  (void)in_sizes; (void)n_in; (void)out_size; (void)ws_size;
  const float* x    = (const float*)d_in[0];
  const int*   mod  = (const int*)d_in[1];
  const float* A_W1 = (const float*)d_in[2];
  const float* A_b1 = (const float*)d_in[3];
  const float* A_W2 = (const float*)d_in[4];
  const float* A_b2 = (const float*)d_in[5];
  const float* B_W1 = (const float*)d_in[6];
  const float* B_b1 = (const float*)d_in[7];
  const float* B_g  = (const float*)d_in[8];
  const float* B_be = (const float*)d_in[9];
  const float* B_W2 = (const float*)d_in[10];
  const float* B_b2 = (const float*)d_in[11];
  const float* C_cw = (const float*)d_in[12];
  const float* C_cb = (const float*)d_in[13];
  const float* C_W  = (const float*)d_in[14];
  const float* C_b  = (const float*)d_in[15];
  const float* D_W1 = (const float*)d_in[16];
  const float* D_b1 = (const float*)d_in[17];
  const float* D_g  = (const float*)d_in[18];
  const float* D_be = (const float*)d_in[19];
  const float* D_W2 = (const float*)d_in[20];
  const float* D_b2 = (const float*)d_in[21];
  const float* S_W1 = (const float*)d_in[22];
  const float* S_b1 = (const float*)d_in[23];
  const float* S_g  = (const float*)d_in[24];
  const float* S_be = (const float*)d_in[25];
  const float* S_W2 = (const float*)d_in[26];
  const float* S_b2 = (const float*)d_in[27];
  const float* G_W1 = (const float*)d_in[28];
  const float* G_b1 = (const float*)d_in[29];
  const float* G_W2 = (const float*)d_in[30];
  const float* G_b2 = (const float*)d_in[31];

  char* ws = (char*)d_ws;
  unsigned short* W1cat = (unsigned short*)(ws + OFF_W1CAT);
  unsigned short* W2cat = (unsigned short*)(ws + OFF_W2CAT);
  float* W1T    = (float*)(ws + OFF_W1T);
  float* b1cat  = (float*)(ws + OFF_B1);
  float* b2cat  = (float*)(ws + OFF_B2);
  float* lng    = (float*)(ws + OFF_LNG);
  float* lnb    = (float*)(ws + OFF_LNB);
  float* bsc    = (float*)(ws + OFF_BSC);
  float* bbi    = (float*)(ws + OFF_BBI);
  float* usage  = (float*)(ws + OFF_USAGE);
  float* w8full = (float*)(ws + OFF_W8);
  float* out    = (float*)d_out;

  prep_kernel<<<1742, 256, 0, stream>>>(A_W1, A_b1, A_W2, A_b2, B_W1, B_b1, B_g, B_be,
      B_W2, B_b2, C_cw, C_cb, C_W, C_b, D_W1, D_b1, D_g, D_be, D_W2, D_b2,
      S_W1, S_b1, S_g, S_be, S_W2, S_b2, G_W1,
      W1cat, W2cat, W1T, b1cat, b2cat, lng, lnb, bsc, bbi, usage);
  prep2_kernel<<<4, 256, 0, stream>>>(C_cw, C_cb, C_W, b1cat);
  gate_np_kernel<<<512, 512, 0, stream>>>(x, mod, W1T, G_b1, G_W2, G_b2,
      w8full, usage);
  moe_kernel<<<256, 512, 0, stream>>>(x, W1cat, W2cat, b1cat, b2cat, lng, lnb,
      bsc, bbi, w8full, out);
  aux_kernel<<<1, 64, 0, stream>>>(usage, out);
}